// Round 7
// baseline (231.130 us; speedup 1.0000x reference)
//
#include <hip/hip_runtime.h>
#include <hip/hip_bf16.h>
#include <math.h>

#define NW 100000
#define NT 800
#define ND 8000
#define NB 16
#define H 128
#define HINP 300
#define VOCAB 15000
#define NTOPIC 50

typedef __hip_bfloat16 bf16;
typedef __attribute__((ext_vector_type(8))) short bf16x8v;
typedef __attribute__((ext_vector_type(4))) float f32x4;

// per-etype CSR-build parameters
struct Et {
    const int* src; const int* dst; const float* w; const int* remap;
    int* cnt; int* off; int* bktcur; int* bkbase; uint2* scratch; uint2* cs;
    int E, lg, nbkt, stride, ndst;
};

#define EPB 2048  // edges per F1 block

// ==================== device helpers ====================
__device__ inline int wave_incl_scan(int v) {
    for (int off = 1; off < 64; off <<= 1) {
        int t = __shfl_up(v, off);
        if ((threadIdx.x & 63) >= off) v += t;
    }
    return v;
}

__device__ inline void mm128_dev(const float* A, const float* B, float* C, int lb) {
    int tid = lb * 256 + threadIdx.x;
    int i = tid >> 7, j = tid & 127;
    float acc = 0.f;
#pragma unroll 8
    for (int k = 0; k < 128; k++) acc += A[i * 128 + k] * B[k * 128 + j];
    C[tid] = acc;
}

__device__ inline void vecmat_half(const float* v, const float* M, const float* add, float* out) {
    int j = threadIdx.x & 127;
    float acc = add ? add[j] : 0.f;
    for (int k = 0; k < 128; k++) acc += v[k] * M[k * 128 + j];
    out[j] = acc;
}

__device__ inline short bfs(float f) {
    bf16 b = __float2bfloat16(f);
    return *reinterpret_cast<short*>(&b);
}

// 8 bf16 (uint4) * w -> 8 fp32 FMAs
__device__ inline void fma8(uint4 t, unsigned wb,
                            float& a0, float& a1, float& a2, float& a3,
                            float& a4, float& a5, float& a6, float& a7, float& aw) {
    float w = __uint_as_float(wb);
    a0 = fmaf(__uint_as_float(t.x << 16), w, a0);
    a1 = fmaf(__uint_as_float(t.x & 0xffff0000u), w, a1);
    a2 = fmaf(__uint_as_float(t.y << 16), w, a2);
    a3 = fmaf(__uint_as_float(t.y & 0xffff0000u), w, a3);
    a4 = fmaf(__uint_as_float(t.z << 16), w, a4);
    a5 = fmaf(__uint_as_float(t.z & 0xffff0000u), w, a5);
    a6 = fmaf(__uint_as_float(t.w << 16), w, a6);
    a7 = fmaf(__uint_as_float(t.w & 0xffff0000u), w, a7);
    aw += w;
}

__device__ inline unsigned pk2(float f0, float f1) {
    bf16 b0 = __float2bfloat16(f0), b1 = __float2bfloat16(f1);
    unsigned short s0 = *reinterpret_cast<unsigned short*>(&b0);
    unsigned short s1 = *reinterpret_cast<unsigned short*>(&b1);
    return ((unsigned)s1 << 16) | s0;
}

// software-pipelined gather, DEPTH 8 (+ depth-4 drain + scalar tail);
// 16-lane groups, uint4 (16B) loads; p.x pre-scaled src*16
__device__ inline void gpipe16(const uint4* __restrict__ t16, const uint2* __restrict__ csr,
                               int e, int e1, int st, int col,
                               float& a0, float& a1, float& a2, float& a3,
                               float& a4, float& a5, float& a6, float& a7, float& aw) {
    if (e + 7 * st < e1) {
        uint2 p0 = csr[e], p1 = csr[e + st], p2 = csr[e + 2 * st], p3 = csr[e + 3 * st];
        uint2 p4 = csr[e + 4 * st], p5 = csr[e + 5 * st], p6 = csr[e + 6 * st], p7 = csr[e + 7 * st];
        e += 8 * st;
        while (e + 7 * st < e1) {
            uint4 t0 = t16[p0.x + col], t1 = t16[p1.x + col];
            uint4 t2 = t16[p2.x + col], t3 = t16[p3.x + col];
            uint4 t4 = t16[p4.x + col], t5 = t16[p5.x + col];
            uint4 t6 = t16[p6.x + col], t7 = t16[p7.x + col];
            uint2 q0 = csr[e], q1 = csr[e + st], q2 = csr[e + 2 * st], q3 = csr[e + 3 * st];
            uint2 q4 = csr[e + 4 * st], q5 = csr[e + 5 * st], q6 = csr[e + 6 * st], q7 = csr[e + 7 * st];
            fma8(t0, p0.y, a0, a1, a2, a3, a4, a5, a6, a7, aw);
            fma8(t1, p1.y, a0, a1, a2, a3, a4, a5, a6, a7, aw);
            fma8(t2, p2.y, a0, a1, a2, a3, a4, a5, a6, a7, aw);
            fma8(t3, p3.y, a0, a1, a2, a3, a4, a5, a6, a7, aw);
            fma8(t4, p4.y, a0, a1, a2, a3, a4, a5, a6, a7, aw);
            fma8(t5, p5.y, a0, a1, a2, a3, a4, a5, a6, a7, aw);
            fma8(t6, p6.y, a0, a1, a2, a3, a4, a5, a6, a7, aw);
            fma8(t7, p7.y, a0, a1, a2, a3, a4, a5, a6, a7, aw);
            p0 = q0; p1 = q1; p2 = q2; p3 = q3;
            p4 = q4; p5 = q5; p6 = q6; p7 = q7;
            e += 8 * st;
        }
        uint4 t0 = t16[p0.x + col], t1 = t16[p1.x + col];
        uint4 t2 = t16[p2.x + col], t3 = t16[p3.x + col];
        uint4 t4 = t16[p4.x + col], t5 = t16[p5.x + col];
        uint4 t6 = t16[p6.x + col], t7 = t16[p7.x + col];
        fma8(t0, p0.y, a0, a1, a2, a3, a4, a5, a6, a7, aw);
        fma8(t1, p1.y, a0, a1, a2, a3, a4, a5, a6, a7, aw);
        fma8(t2, p2.y, a0, a1, a2, a3, a4, a5, a6, a7, aw);
        fma8(t3, p3.y, a0, a1, a2, a3, a4, a5, a6, a7, aw);
        fma8(t4, p4.y, a0, a1, a2, a3, a4, a5, a6, a7, aw);
        fma8(t5, p5.y, a0, a1, a2, a3, a4, a5, a6, a7, aw);
        fma8(t6, p6.y, a0, a1, a2, a3, a4, a5, a6, a7, aw);
        fma8(t7, p7.y, a0, a1, a2, a3, a4, a5, a6, a7, aw);
    }
    if (e + 3 * st < e1) {
        uint2 p0 = csr[e], p1 = csr[e + st], p2 = csr[e + 2 * st], p3 = csr[e + 3 * st];
        uint4 t0 = t16[p0.x + col], t1 = t16[p1.x + col];
        uint4 t2 = t16[p2.x + col], t3 = t16[p3.x + col];
        fma8(t0, p0.y, a0, a1, a2, a3, a4, a5, a6, a7, aw);
        fma8(t1, p1.y, a0, a1, a2, a3, a4, a5, a6, a7, aw);
        fma8(t2, p2.y, a0, a1, a2, a3, a4, a5, a6, a7, aw);
        fma8(t3, p3.y, a0, a1, a2, a3, a4, a5, a6, a7, aw);
        e += 4 * st;
    }
    for (; e < e1; e += st) {
        uint2 p = csr[e];
        uint4 t = t16[p.x + col];
        fma8(t, p.y, a0, a1, a2, a3, a4, a5, a6, a7, aw);
    }
}

// ==================== K1: F1 bin pass (vectorized, 2048 edges/block) | prep level-1 ====================
__device__ inline void f1_run(const Et& a, int blk) {
    __shared__ int cnt[256], base[256];
    int e0 = blk * EPB;
    for (int i = threadIdx.x; i < a.nbkt; i += 256) cnt[i] = 0;
    __syncthreads();
    // phase A: vector-load dst (kept in regs), LDS histogram
    int4 d4[2];
#pragma unroll
    for (int c = 0; c < 2; c++) {
        int e = e0 + c * 1024 + threadIdx.x * 4;
        int4 d;
        if (e + 3 < a.E) {
            d = *reinterpret_cast<const int4*>(&a.dst[e]);
        } else {
            d.x = (e < a.E) ? a.dst[e] : -1;
            d.y = (e + 1 < a.E) ? a.dst[e + 1] : -1;
            d.z = (e + 2 < a.E) ? a.dst[e + 2] : -1;
            d.w = (e + 3 < a.E) ? a.dst[e + 3] : -1;
        }
        d4[c] = d;
        if (d.x >= 0) atomicAdd(&cnt[d.x >> a.lg], 1);
        if (d.y >= 0) atomicAdd(&cnt[d.y >> a.lg], 1);
        if (d.z >= 0) atomicAdd(&cnt[d.z >> a.lg], 1);
        if (d.w >= 0) atomicAdd(&cnt[d.w >> a.lg], 1);
    }
    __syncthreads();
    for (int i = threadIdx.x; i < a.nbkt; i += 256)
        base[i] = cnt[i] ? atomicAdd(&a.bktcur[i], cnt[i]) : 0;
    __syncthreads();
    for (int i = threadIdx.x; i < a.nbkt; i += 256) cnt[i] = base[i];
    __syncthreads();
    // phase B: vector-load src/w, remap-gather, scatter
    unsigned msk = (1u << a.lg) - 1;
#pragma unroll
    for (int c = 0; c < 2; c++) {
        int e = e0 + c * 1024 + threadIdx.x * 4;
        int4 d = d4[c];
        int4 s4;
        float4 w4;
        if (e + 3 < a.E) {
            s4 = *reinterpret_cast<const int4*>(&a.src[e]);
            w4 = *reinterpret_cast<const float4*>(&a.w[e]);
        } else {
            s4.x = (e < a.E) ? a.src[e] : 0;
            s4.y = (e + 1 < a.E) ? a.src[e + 1] : 0;
            s4.z = (e + 2 < a.E) ? a.src[e + 2] : 0;
            s4.w = (e + 3 < a.E) ? a.src[e + 3] : 0;
            w4.x = (e < a.E) ? a.w[e] : 0.f;
            w4.y = (e + 1 < a.E) ? a.w[e + 1] : 0.f;
            w4.z = (e + 2 < a.E) ? a.w[e + 2] : 0.f;
            w4.w = (e + 3 < a.E) ? a.w[e + 3] : 0.f;
        }
        if (a.remap) {
            if (d.x >= 0) s4.x = a.remap[s4.x];
            if (d.y >= 0) s4.y = a.remap[s4.y];
            if (d.z >= 0) s4.z = a.remap[s4.z];
            if (d.w >= 0) s4.w = a.remap[s4.w];
        }
        {
            int dd = d.x;
            if (dd >= 0) {
                int bb = dd >> a.lg;
                int p = atomicAdd(&cnt[bb], 1);
                if (p < a.stride)
                    a.scratch[(size_t)bb * a.stride + p] =
                        make_uint2((unsigned)s4.x | (((unsigned)dd & msk) << 17), __float_as_uint(w4.x));
            }
        }
        {
            int dd = d.y;
            if (dd >= 0) {
                int bb = dd >> a.lg;
                int p = atomicAdd(&cnt[bb], 1);
                if (p < a.stride)
                    a.scratch[(size_t)bb * a.stride + p] =
                        make_uint2((unsigned)s4.y | (((unsigned)dd & msk) << 17), __float_as_uint(w4.y));
            }
        }
        {
            int dd = d.z;
            if (dd >= 0) {
                int bb = dd >> a.lg;
                int p = atomicAdd(&cnt[bb], 1);
                if (p < a.stride)
                    a.scratch[(size_t)bb * a.stride + p] =
                        make_uint2((unsigned)s4.z | (((unsigned)dd & msk) << 17), __float_as_uint(w4.z));
            }
        }
        {
            int dd = d.w;
            if (dd >= 0) {
                int bb = dd >> a.lg;
                int p = atomicAdd(&cnt[bb], 1);
                if (p < a.stride)
                    a.scratch[(size_t)bb * a.stride + p] =
                        make_uint2((unsigned)s4.w | (((unsigned)dd & msk) << 17), __float_as_uint(w4.w));
            }
        }
    }
}

__global__ void k1_kernel(Et a0, Et a1, Et a2, Et a3, Et a4,
                          int f0, int f1b, int f2b, int f3b, int f4b,
                          const float* W1, const float* b1, const float* W2, const float* b2,
                          const float* Wa, const float* ba,
                          float* U1, float* V1, float* A_t1, float* X2, float* A_t2,
                          float* t1, float* u, float* t2, float* b_t1, float* b_t2) {
    int b = blockIdx.x;
    if (b < f0) f1_run(a0, b);
    else if (b < f1b) f1_run(a1, b - f0);
    else if (b < f2b) f1_run(a2, b - f1b);
    else if (b < f3b) f1_run(a3, b - f2b);
    else if (b < f4b) f1_run(a4, b - f3b);
    else {
        int pb = b - f4b;
        if (pb < 150) mm128_dev(Wa, W1, U1, pb);                                    // U1 = Wa@W1_0
        else if (pb < 214) mm128_dev(W1 + 16384, W1 + 2 * 16384, V1, pb - 150);     // V1 = W1_1@W1_2
        else if (pb < 278) mm128_dev(W1 + 3 * 16384, W1 + 4 * 16384, A_t1, pb - 214);
        else if (pb < 342) mm128_dev(W2, W2 + 16384, X2, pb - 278);                 // X2 = W2_0@W2_1
        else if (pb < 406) mm128_dev(W2 + 3 * 16384, W2 + 4 * 16384, A_t2, pb - 342);
        else if (pb == 406) {
            if (threadIdx.x < 128) vecmat_half(b1, W1 + 16384, b1 + 128, t1);       // t1
            else vecmat_half(ba, W1, nullptr, u);                                   // u = ba@W1_0
        } else if (pb == 407) {
            if (threadIdx.x < 128) vecmat_half(b1 + 3 * 128, W1 + 4 * 16384, b1 + 4 * 128, b_t1);
            else vecmat_half(b2, W2 + 16384, b2 + 128, t2);                         // t2
        } else {
            if (threadIdx.x < 128) vecmat_half(b2 + 3 * 128, W2 + 4 * 16384, b2 + 4 * 128, b_t2);
        }
    }
}

// ==================== K2: bucket scans | prep level-2 ====================
__device__ inline void bkscan_run(const Et& a) {
    __shared__ int wsum[4];
    int i = threadIdx.x;
    int v = (i < a.nbkt) ? min(a.bktcur[i], a.stride) : 0;
    int incl = wave_incl_scan(v);
    int wv = i >> 6;
    if ((i & 63) == 63) wsum[wv] = incl;
    __syncthreads();
    int base = 0;
    for (int k = 0; k < wv; k++) base += wsum[k];
    if (i < a.nbkt) a.bkbase[i] = incl + base - v;
}

__global__ void k2_kernel(Et a0, Et a1, Et a2, Et a3, Et a4,
                          const float* W1, const float* b1, const float* W2, const float* b2,
                          const float* U1, const float* V1, const float* X2,
                          const float* t1, const float* u, const float* t2,
                          bf16* P1t, float* A_w2, float* bv1, float* b_w2) {
    int b = blockIdx.x;
    if (b == 0) bkscan_run(a0);
    else if (b == 1) bkscan_run(a1);
    else if (b == 2) bkscan_run(a2);
    else if (b == 3) bkscan_run(a3);
    else if (b == 4) bkscan_run(a4);
    else {
        int pb = b - 5;
        if (pb < 150) {
            // P1 = U1@V1, stored TRANSPOSED bf16 [128][320] (pad zeroed by memset)
            int tid = pb * 256 + threadIdx.x;
            int i = tid >> 7, j = tid & 127;
            float acc = 0.f;
#pragma unroll 8
            for (int k = 0; k < 128; k++) acc += U1[i * 128 + k] * V1[k * 128 + j];
            P1t[(size_t)j * 320 + i] = __float2bfloat16(acc);
        } else if (pb < 214) {
            mm128_dev(X2, W2 + 2 * 16384, A_w2, pb - 150);                          // A_w2 = X2@W2_2
        } else {
            int j = threadIdx.x & 127;
            if (threadIdx.x < 128) {
                float acc = b1[2 * 128 + j];
                for (int k = 0; k < 128; k++)
                    acc += u[k] * V1[k * 128 + j] + t1[k] * W1[2 * 16384 + k * 128 + j];
                bv1[j] = acc;
            } else {
                float acc = b2[2 * 128 + j];
                for (int k = 0; k < 128; k++) acc += t2[k] * W2[2 * 16384 + k * 128 + j];
                b_w2[j] = acc;
            }
        }
    }
}

// ==================== K3: pv (MFMA) | pt | F2 CSR pass ====================
__device__ inline void f2_run(const Et& a, int blk, int* lhist, int* lcur, int* wsc) {
    int d0 = blk << a.lg;
    int nd = min(1 << a.lg, a.ndst - d0);
    int nE = min(a.bktcur[blk], a.stride);
    int base = a.bkbase[blk];
    const uint2* sc = a.scratch + (size_t)blk * a.stride;
    for (int i = threadIdx.x; i < nd; i += 256) lhist[i] = 0;
    __syncthreads();
    for (int e = threadIdx.x; e < nE; e += 256) atomicAdd(&lhist[sc[e].x >> 17], 1);
    __syncthreads();
    int per = (nd + 255) >> 8;
    int i0 = threadIdx.x * per;
    int s = 0;
    for (int k = 0; k < per; k++) {
        int i = i0 + k;
        if (i < nd) s += lhist[i];
    }
    int incl = wave_incl_scan(s);
    int wv = threadIdx.x >> 6;
    if ((threadIdx.x & 63) == 63) wsc[wv] = incl;
    __syncthreads();
    int wbase = 0;
    for (int k = 0; k < wv; k++) wbase += wsc[k];
    int run = wbase + incl - s;
    for (int k = 0; k < per; k++) {
        int i = i0 + k;
        if (i < nd) {
            int c = lhist[i];
            lcur[i] = run;
            a.cnt[d0 + i] = c;
            a.off[d0 + i] = base + run;
            run += c;
        }
    }
    __syncthreads();
    for (int e = threadIdx.x; e < nE; e += 256) {
        uint2 v = sc[e];
        int dl = v.x >> 17;
        int p = atomicAdd(&lcur[dl], 1);
        a.cs[base + p] = make_uint2((v.x & 0x1FFFFu) * 16u, v.y);  // pre-scaled src*16 (uint4 units)
    }
}

#define NBPVM 235  // ceil(VOCAB/64)
#define NBPT 25    // ceil(NTOPIC/2)

__global__ void k3_kernel(Et a0, Et a1, Et a2, Et a3, Et a4,
                          int g0, int g1, int g2, int g3, int g4,
                          const float* __restrict__ emb, const bf16* __restrict__ P1t,
                          const float* __restrict__ bv1, bf16* __restrict__ pv1,
                          const float* te, const float* A_t1, const float* b_t1, bf16* pt1) {
    __shared__ int sh[1028];
    int b = blockIdx.x;
    if (b < NBPVM) {
        // ---- pv via MFMA: 64 rows/block, wave w -> rows w*16..w*16+15, all 128 cols ----
        int wv = threadIdx.x >> 6, lane = threadIdx.x & 63;
        int r16 = lane & 15, g16 = lane >> 4;  // fragment row / k-group
        int rowbase = b * 64 + wv * 16;
        int arow = rowbase + r16;
        bool rok = arow < VOCAB;
        const size_t embrow = (size_t)arow * HINP;
        f32x4 acc[8];
#pragma unroll
        for (int c = 0; c < 8; c++) acc[c] = (f32x4){0.f, 0.f, 0.f, 0.f};
#pragma unroll
        for (int s = 0; s < 10; s++) {
            int k0 = s * 32 + g16 * 8;
            bf16x8v af;
            if (rok && k0 + 8 <= HINP) {
                float4 lo = *reinterpret_cast<const float4*>(&emb[embrow + k0]);
                float4 hi = *reinterpret_cast<const float4*>(&emb[embrow + k0 + 4]);
                af[0] = bfs(lo.x); af[1] = bfs(lo.y); af[2] = bfs(lo.z); af[3] = bfs(lo.w);
                af[4] = bfs(hi.x); af[5] = bfs(hi.y); af[6] = bfs(hi.z); af[7] = bfs(hi.w);
            } else if (rok && k0 < HINP) {
#pragma unroll
                for (int j = 0; j < 8; j++)
                    af[j] = (k0 + j < HINP) ? bfs(emb[embrow + k0 + j]) : (short)0;
            } else {
#pragma unroll
                for (int j = 0; j < 8; j++) af[j] = 0;
            }
#pragma unroll
            for (int c = 0; c < 8; c++) {
                int col = c * 16 + r16;
                bf16x8v bf = *reinterpret_cast<const bf16x8v*>(&P1t[(size_t)col * 320 + s * 32 + g16 * 8]);
                acc[c] = __builtin_amdgcn_mfma_f32_16x16x32_bf16(af, bf, acc[c], 0, 0, 0);
            }
        }
        // epilogue: D col = lane&15, row = (lane>>4)*4 + reg  [m89-verified]
        int orow0 = rowbase + g16 * 4;
#pragma unroll
        for (int c = 0; c < 8; c++) {
            int col = c * 16 + r16;
            float bv = bv1[col];
#pragma unroll
            for (int r = 0; r < 4; r++) {
                int row = orow0 + r;
                if (row < VOCAB) pv1[(size_t)row * 128 + col] = __float2bfloat16(acc[c][r] + bv);
            }
        }
        return;
    }
    if (b < NBPVM + NBPT) {
        int half = threadIdx.x >> 7, j = threadIdx.x & 127;
        int r = (b - NBPVM) * 2 + half;
        if (r < NTOPIC) {
            float acc = b_t1[j];
            for (int k = 0; k < 128; k++) acc += te[r * 128 + k] * A_t1[k * 128 + j];
            pt1[r * 128 + j] = __float2bfloat16(acc);
        }
        return;
    }
    int fb = b - NBPVM - NBPT;
    int* lhist = sh;
    int* lcur = sh + 512;
    int* wsc = sh + 1024;
    if (fb < g0) f2_run(a0, fb, lhist, lcur, wsc);
    else if (fb < g1) f2_run(a1, fb - g0, lhist, lcur, wsc);
    else if (fb < g2) f2_run(a2, fb - g1, lhist, lcur, wsc);
    else if (fb < g3) f2_run(a3, fb - g2, lhist, lcur, wsc);
    else f2_run(a4, fb - g3, lhist, lcur, wsc);
}

#define RED2(x) { x += __shfl_down(x, 16); x += __shfl_down(x, 32); }
#define RED1(x) { x += __shfl_down(x, 16); }

// ==================== K4: layer-1 aggregation (16-lane groups, uint4 gathers) ====================
__global__ __launch_bounds__(256, 8)
void aggA_kernel(const uint4* __restrict__ pv16, const uint4* __restrict__ pt16,
                 const uint2* __restrict__ cs_ww, const int* __restrict__ off_ww,
                 const int* __restrict__ cnt_ww, uint4* __restrict__ hw16,
                 const uint2* __restrict__ cs_wt, const int* __restrict__ off_wt,
                 const int* __restrict__ cnt_wt,
                 const uint2* __restrict__ cs_tt, const int* __restrict__ off_tt,
                 const int* __restrict__ cnt_tt, uint4* __restrict__ ht16) {
    __shared__ float redA[4][16][8], redC[4][16][8];
    int b = blockIdx.x;
    int wv = threadIdx.x >> 6;
    int lane = threadIdx.x & 63;
    int col = threadIdx.x & 15;
    if (b >= NT) {
        // word rows: 16 rows/block, one 16-lane group per row
        int row = (b - NT) * 16 + (threadIdx.x >> 4);
        int e = off_ww[row], n = cnt_ww[row];
        float a0 = 0.f, a1 = 0.f, a2 = 0.f, a3 = 0.f;
        float a4 = 0.f, a5 = 0.f, a6 = 0.f, a7 = 0.f, aw = 0.f;
        gpipe16(pv16, cs_ww, e, e + n, 1, col, a0, a1, a2, a3, a4, a5, a6, a7, aw);
        float inv = 1.f / fmaxf((float)n, 1.f);
        uint4 o;
        o.x = pk2(fmaxf(a0 * inv, 0.f), fmaxf(a1 * inv, 0.f));
        o.y = pk2(fmaxf(a2 * inv, 0.f), fmaxf(a3 * inv, 0.f));
        o.z = pk2(fmaxf(a4 * inv, 0.f), fmaxf(a5 * inv, 0.f));
        o.w = pk2(fmaxf(a6 * inv, 0.f), fmaxf(a7 * inv, 0.f));
        hw16[(size_t)row * 16 + col] = o;
        return;
    }
    // topic row: one row per block, 16 substreams (one per 16-lane group)
    int row = b;
    int g = threadIdx.x >> 4;
    int e0 = off_wt[row], n1 = cnt_wt[row];
    float a0 = 0.f, a1 = 0.f, a2 = 0.f, a3 = 0.f;
    float a4 = 0.f, a5 = 0.f, a6 = 0.f, a7 = 0.f, aw = 0.f;
    gpipe16(pv16, cs_wt, e0 + g, e0 + n1, 16, col, a0, a1, a2, a3, a4, a5, a6, a7, aw);
    int f0 = off_tt[row], n2 = cnt_tt[row];
    float c0 = 0.f, c1 = 0.f, c2 = 0.f, c3 = 0.f;
    float c4 = 0.f, c5 = 0.f, c6 = 0.f, c7 = 0.f, cw = 0.f;
    gpipe16(pt16, cs_tt, f0 + g, f0 + n2, 16, col, c0, c1, c2, c3, c4, c5, c6, c7, cw);
    RED2(a0); RED2(a1); RED2(a2); RED2(a3); RED2(a4); RED2(a5); RED2(a6); RED2(a7);
    RED2(c0); RED2(c1); RED2(c2); RED2(c3); RED2(c4); RED2(c5); RED2(c6); RED2(c7);
    if (lane < 16) {
        redA[wv][col][0] = a0; redA[wv][col][1] = a1; redA[wv][col][2] = a2; redA[wv][col][3] = a3;
        redA[wv][col][4] = a4; redA[wv][col][5] = a5; redA[wv][col][6] = a6; redA[wv][col][7] = a7;
        redC[wv][col][0] = c0; redC[wv][col][1] = c1; redC[wv][col][2] = c2; redC[wv][col][3] = c3;
        redC[wv][col][4] = c4; redC[wv][col][5] = c5; redC[wv][col][6] = c6; redC[wv][col][7] = c7;
    }
    __syncthreads();
    if (threadIdx.x < 16) {
        float A[8], C[8];
#pragma unroll
        for (int d = 0; d < 8; d++) { A[d] = redA[0][col][d]; C[d] = redC[0][col][d]; }
#pragma unroll
        for (int k = 1; k < 4; k++)
#pragma unroll
            for (int d = 0; d < 8; d++) { A[d] += redA[k][col][d]; C[d] += redC[k][col][d]; }
        float i1 = 1.f / fmaxf((float)n1, 1.f);
        float i2 = 1.f / fmaxf((float)n2, 1.f);
        uint4 o;
        o.x = pk2(fmaxf(A[0] * i1 + C[0] * i2, 0.f), fmaxf(A[1] * i1 + C[1] * i2, 0.f));
        o.y = pk2(fmaxf(A[2] * i1 + C[2] * i2, 0.f), fmaxf(A[3] * i1 + C[3] * i2, 0.f));
        o.z = pk2(fmaxf(A[4] * i1 + C[4] * i2, 0.f), fmaxf(A[5] * i1 + C[5] * i2, 0.f));
        o.w = pk2(fmaxf(A[6] * i1 + C[6] * i2, 0.f), fmaxf(A[7] * i1 + C[7] * i2, 0.f));
        ht16[(size_t)row * 16 + col] = o;
    }
}

// ==================== K5: fused layer-2 aggregation + doc projection ====================
__global__ __launch_bounds__(256, 8)
void aggBdoc_kernel(const uint4* __restrict__ hw16, const uint4* __restrict__ ht16,
                    const uint2* __restrict__ c_wd, const int* __restrict__ o_wd,
                    const int* __restrict__ n_wd,
                    const uint2* __restrict__ c_td, const int* __restrict__ o_td,
                    const int* __restrict__ n_td,
                    const float* __restrict__ A_w2, const float* __restrict__ b_w2,
                    const float* __restrict__ A_t2, const float* __restrict__ b_t2,
                    float* __restrict__ hd) {
    __shared__ float ld1[8][128], ld2[8][128];
    __shared__ float swc[8][4];
    int d0 = blockIdx.x * 8;
    int wv = threadIdx.x >> 6;
    int lane = threadIdx.x & 63;
    int col = threadIdx.x & 15;
    int lr = wv * 2 + (lane >> 5);     // doc 0..7 within block
    int sid = (lane >> 4) & 1;         // 2 substreams per doc
    int row = d0 + lr;
    {
        int e = o_wd[row], n = n_wd[row];
        float a0 = 0.f, a1 = 0.f, a2 = 0.f, a3 = 0.f;
        float a4 = 0.f, a5 = 0.f, a6 = 0.f, a7 = 0.f, aw = 0.f;
        gpipe16(hw16, c_wd, e + sid, e + n, 2, col, a0, a1, a2, a3, a4, a5, a6, a7, aw);
        RED1(a0); RED1(a1); RED1(a2); RED1(a3);
        RED1(a4); RED1(a5); RED1(a6); RED1(a7); RED1(aw);
        if ((lane & 31) < 16) {
            float* p = &ld1[lr][col * 8];
            p[0] = a0; p[1] = a1; p[2] = a2; p[3] = a3;
            p[4] = a4; p[5] = a5; p[6] = a6; p[7] = a7;
            if (col == 0) { swc[lr][0] = aw; swc[lr][1] = (float)n; }
        }
    }
    {
        int e = o_td[row], n = n_td[row];
        float a0 = 0.f, a1 = 0.f, a2 = 0.f, a3 = 0.f;
        float a4 = 0.f, a5 = 0.f, a6 = 0.f, a7 = 0.f, aw = 0.f;
        gpipe16(ht16, c_td, e + sid, e + n, 2, col, a0, a1, a2, a3, a4, a5, a6, a7, aw);
        RED1(a0); RED1(a1); RED1(a2); RED1(a3);
        RED1(a4); RED1(a5); RED1(a6); RED1(a7); RED1(aw);
        if ((lane & 31) < 16) {
            float* p = &ld2[lr][col * 8];
            p[0] = a0; p[1] = a1; p[2] = a2; p[3] = a3;
            p[4] = a4; p[5] = a5; p[6] = a6; p[7] = a7;
            if (col == 0) { swc[lr][2] = aw; swc[lr][3] = (float)n; }
        }
    }
    __syncthreads();
    int j = threadIdx.x & 127, hf = threadIdx.x >> 7;
    const float* L1 = &ld1[0][0];
    const float* L2 = &ld2[0][0];
    float a1v[4] = {0.f, 0.f, 0.f, 0.f}, a2v[4] = {0.f, 0.f, 0.f, 0.f};
    for (int k = 0; k < 128; k++) {
        float w1 = A_w2[k * 128 + j];
        float w2 = A_t2[k * 128 + j];
#pragma unroll
        for (int r = 0; r < 4; r++) {
            a1v[r] += L1[(hf * 4 + r) * 128 + k] * w1;
            a2v[r] += L2[(hf * 4 + r) * 128 + k] * w2;
        }
    }
    float bw = b_w2[j], bt = b_t2[j];
#pragma unroll
    for (int r = 0; r < 4; r++) {
        int rr = hf * 4 + r;
        float cc1 = fmaxf(swc[rr][1], 1.f), cc2 = fmaxf(swc[rr][3], 1.f);
        float v = (a1v[r] + bw * swc[rr][0]) / cc1 + (a2v[r] + bt * swc[rr][2]) / cc2;
        hd[(size_t)(d0 + rr) * 128 + j] = fmaxf(v, 0.f);
    }
}

// K6: doc pool — one block per graph
__global__ void docpool_kernel(const float* __restrict__ hd, const int* __restrict__ gid,
                               float* __restrict__ part) {
    __shared__ float red[8][128];
    int b = blockIdx.x;
    int r = threadIdx.x >> 7;
    int j = threadIdx.x & 127;
    const int DPG = ND / NB;
    int d0 = b * DPG, d1 = d0 + DPG;
    float m = -INFINITY;
    for (int d = d0 + r; d < d1; d += 8) {
        if (gid[d] == b) m = fmaxf(m, hd[(size_t)d * 128 + j]);
    }
    red[r][j] = m;
    __syncthreads();
    if (r == 0) {
#pragma unroll
        for (int k = 1; k < 8; k++) m = fmaxf(m, red[k][j]);
        part[b * 128 + j] = m;
    }
}

// K7: final: logits -> loss + sigmoid
__global__ void final_kernel(const float* __restrict__ part, const float* __restrict__ Wo,
                             const float* __restrict__ bo, const float* __restrict__ y,
                             float* __restrict__ out) {
    __shared__ float ls[16];
    int w = threadIdx.x >> 6, lane = threadIdx.x & 63;
    float m0 = part[(size_t)w * 128 + lane];
    float m1 = part[(size_t)w * 128 + 64 + lane];
    float p = m0 * Wo[lane] + m1 * Wo[64 + lane];
#pragma unroll
    for (int off = 32; off > 0; off >>= 1) p += __shfl_down(p, off);
    if (lane == 0) ls[w] = p + bo[0];
    __syncthreads();
    if (threadIdx.x < 16) {
        float l = ls[threadIdx.x];
        out[1 + threadIdx.x] = 1.f / (1.f + expf(-l));
    }
    if (threadIdx.x == 0) {
        float s = 0.f;
        for (int b = 0; b < 16; b++) {
            float l = ls[b];
            s += fmaxf(l, 0.f) - l * y[b] + log1pf(expf(-fabsf(l)));
        }
        out[0] = s / 16.f;
    }
}

extern "C" void kernel_launch(void* const* d_in, const int* in_sizes, int n_in,
                              void* d_out, int out_size, void* d_ws, size_t ws_size,
                              hipStream_t stream) {
    const int* word_ids = (const int*)d_in[0];
    const int* topic_ids = (const int*)d_in[1];
    const int* doc_graph_id = (const int*)d_in[2];
    const int* ww_src = (const int*)d_in[3];
    const int* ww_dst = (const int*)d_in[4];
    const float* ww_w = (const float*)d_in[5];
    const int* wt_src = (const int*)d_in[6];
    const int* wt_dst = (const int*)d_in[7];
    const float* wt_w = (const float*)d_in[8];
    const int* wd_src = (const int*)d_in[9];
    const int* wd_dst = (const int*)d_in[10];
    const float* wd_w = (const float*)d_in[11];
    const int* td_src = (const int*)d_in[12];
    const int* td_dst = (const int*)d_in[13];
    const float* td_w = (const float*)d_in[14];
    const int* tt_src = (const int*)d_in[15];
    const int* tt_dst = (const int*)d_in[16];
    const float* tt_w = (const float*)d_in[17];
    const float* word_embeds = (const float*)d_in[18];
    const float* topic_embeds = (const float*)d_in[19];
    const float* W_adapt = (const float*)d_in[20];
    const float* b_adapt = (const float*)d_in[21];
    const float* W1 = (const float*)d_in[22];
    const float* b1 = (const float*)d_in[23];
    const float* W2 = (const float*)d_in[24];
    const float* b2 = (const float*)d_in[25];
    const float* W_out = (const float*)d_in[26];
    const float* b_out = (const float*)d_in[27];
    const float* y_data = (const float*)d_in[28];
    float* out = (float*)d_out;

    const int E_ww = in_sizes[3], E_wt = in_sizes[6], E_wd = in_sizes[9];
    const int E_td = in_sizes[12], E_tt = in_sizes[15];

    // bucket configs: {lg, nbkt, stride}
    const int LG_WW = 9, NBK_WW = 196, ST_WW = 6144;
    const int LG_WT = 4, NBK_WT = 50,  ST_WT = 6656;
    const int LG_TT = 6, NBK_TT = 13,  ST_TT = 3712;
    const int LG_WD = 6, NBK_WD = 125, ST_WD = 4608;
    const int LG_TD = 8, NBK_TD = 32,  ST_TD = 3712;

    // -------- workspace --------
    float* ws = (float*)d_ws;
    size_t o = 0;
    auto alloc = [&](size_t n) { float* p = ws + o; o += (n + 63) & ~(size_t)63; return p; };
    bf16* pv1 = (bf16*)alloc((size_t)VOCAB * 64);
    bf16* pt1 = (bf16*)alloc((size_t)NTOPIC * 64);
    bf16* hw1 = (bf16*)alloc((size_t)NW * 64);
    bf16* ht1 = (bf16*)alloc((size_t)NT * 64);
    float* hd = alloc((size_t)ND * 128);
    // zeroed region: bucket cursors + P1t (pad must be zero)
    int* bk_ww = (int*)alloc(NBK_WW);
    int* bk_wt = (int*)alloc(NBK_WT);
    int* bk_tt = (int*)alloc(NBK_TT);
    int* bk_wd = (int*)alloc(NBK_WD);
    int* bk_td = (int*)alloc(NBK_TD);
    bf16* P1t = (bf16*)alloc(128 * 320 / 2);   // bf16 [128][320]
    float* zero_end = ws + o;
    int* bkb_ww = (int*)alloc(NBK_WW);
    int* bkb_wt = (int*)alloc(NBK_WT);
    int* bkb_tt = (int*)alloc(NBK_TT);
    int* bkb_wd = (int*)alloc(NBK_WD);
    int* bkb_td = (int*)alloc(NBK_TD);
    int* cnt_ww = (int*)alloc(NW);
    int* cnt_wt = (int*)alloc(NT);
    int* cnt_tt = (int*)alloc(NT);
    int* cnt_wd = (int*)alloc(ND);
    int* cnt_td = (int*)alloc(ND);
    int* off_ww = (int*)alloc(NW);
    int* off_wt = (int*)alloc(NT);
    int* off_tt = (int*)alloc(NT);
    int* off_wd = (int*)alloc(ND);
    int* off_td = (int*)alloc(ND);
    uint2* cs_ww = (uint2*)alloc((size_t)E_ww * 2);
    uint2* cs_wt = (uint2*)alloc((size_t)E_wt * 2);
    uint2* cs_tt = (uint2*)alloc((size_t)E_tt * 2);
    uint2* cs_wd = (uint2*)alloc((size_t)E_wd * 2);
    uint2* cs_td = (uint2*)alloc((size_t)E_td * 2);
    uint2* sc_ww = (uint2*)alloc((size_t)NBK_WW * ST_WW * 2);
    uint2* sc_wt = (uint2*)alloc((size_t)NBK_WT * ST_WT * 2);
    uint2* sc_tt = (uint2*)alloc((size_t)NBK_TT * ST_TT * 2);
    uint2* sc_wd = (uint2*)alloc((size_t)NBK_WD * ST_WD * 2);
    uint2* sc_td = (uint2*)alloc((size_t)NBK_TD * ST_TD * 2);
    float* U1 = alloc(HINP * 128);
    float* V1 = alloc(128 * 128);
    float* X2 = alloc(128 * 128);
    float* A_t1 = alloc(128 * 128);
    float* A_w2 = alloc(128 * 128);
    float* A_t2 = alloc(128 * 128);
    float* t1v = alloc(128);
    float* uv = alloc(128);
    float* t2v = alloc(128);
    float* b_t1 = alloc(128);
    float* b_t2 = alloc(128);
    float* bv1 = alloc(128);
    float* b_w2 = alloc(128);
    float* part = alloc((size_t)NB * 128);
    (void)ws_size; (void)n_in; (void)out_size;

    Et eww = {ww_src, ww_dst, ww_w, word_ids,  cnt_ww, off_ww, bk_ww, bkb_ww, sc_ww, cs_ww, E_ww, LG_WW, NBK_WW, ST_WW, NW};
    Et ewt = {wt_src, wt_dst, wt_w, word_ids,  cnt_wt, off_wt, bk_wt, bkb_wt, sc_wt, cs_wt, E_wt, LG_WT, NBK_WT, ST_WT, NT};
    Et ett = {tt_src, tt_dst, tt_w, topic_ids, cnt_tt, off_tt, bk_tt, bkb_tt, sc_tt, cs_tt, E_tt, LG_TT, NBK_TT, ST_TT, NT};
    Et ewd = {wd_src, wd_dst, wd_w, nullptr,   cnt_wd, off_wd, bk_wd, bkb_wd, sc_wd, cs_wd, E_wd, LG_WD, NBK_WD, ST_WD, ND};
    Et etd = {td_src, td_dst, td_w, nullptr,   cnt_td, off_td, bk_td, bkb_td, sc_td, cs_td, E_td, LG_TD, NBK_TD, ST_TD, ND};

    // -------- memset bucket cursors + P1t pad --------
    hipMemsetAsync(bk_ww, 0, (char*)zero_end - (char*)bk_ww, stream);

    // -------- K1: F1 (2048 edges/block, vectorized) | prep level-1 --------
    int f0 = (E_ww + EPB - 1) / EPB, f1b = f0 + (E_wt + EPB - 1) / EPB;
    int f2b = f1b + (E_tt + EPB - 1) / EPB, f3b = f2b + (E_wd + EPB - 1) / EPB;
    int f4b = f3b + (E_td + EPB - 1) / EPB;
    k1_kernel<<<f4b + 409, 256, 0, stream>>>(eww, ewt, ett, ewd, etd,
                                             f0, f1b, f2b, f3b, f4b,
                                             W1, b1, W2, b2, W_adapt, b_adapt,
                                             U1, V1, A_t1, X2, A_t2,
                                             t1v, uv, t2v, b_t1, b_t2);

    // -------- K2: bucket scans | prep level-2 (emits P1t bf16 transposed) --------
    k2_kernel<<<220, 256, 0, stream>>>(eww, ewt, ett, ewd, etd,
                                       W1, b1, W2, b2, U1, V1, X2, t1v, uv, t2v,
                                       P1t, A_w2, bv1, b_w2);

    // -------- K3: pv MFMA | pt | F2 CSR pass --------
    int g0 = NBK_WW, g1 = g0 + NBK_WT, g2 = g1 + NBK_TT, g3 = g2 + NBK_WD, g4 = g3 + NBK_TD;
    k3_kernel<<<NBPVM + NBPT + g4, 256, 0, stream>>>(
        eww, ewt, ett, ewd, etd, g0, g1, g2, g3, g4,
        word_embeds, P1t, bv1, pv1, topic_embeds, A_t1, b_t1, pt1);

    // -------- K4: layer-1 aggregation (topics first, then ww; 16 word rows/block) --------
    aggA_kernel<<<NT + NW / 16, 256, 0, stream>>>(
        (const uint4*)pv1, (const uint4*)pt1,
        cs_ww, off_ww, cnt_ww, (uint4*)hw1,
        cs_wt, off_wt, cnt_wt,
        cs_tt, off_tt, cnt_tt, (uint4*)ht1);

    // -------- K5: fused layer-2 aggregation + doc projection --------
    aggBdoc_kernel<<<ND / 8, 256, 0, stream>>>(
        (const uint4*)hw1, (const uint4*)ht1,
        cs_wd, off_wd, cnt_wd,
        cs_td, off_td, cnt_td,
        A_w2, b_w2, A_t2, b_t2, hd);

    // -------- readout --------
    docpool_kernel<<<NB, 1024, 0, stream>>>(hd, doc_graph_id, part);
    final_kernel<<<1, 1024, 0, stream>>>(part, W_out, b_out, y_data, out);
}

// Round 8
// 188.038 us; speedup vs baseline: 1.2292x; 1.2292x over previous
//
#include <hip/hip_runtime.h>
#include <hip/hip_bf16.h>
#include <math.h>

#define NW 100000
#define NT 800
#define ND 8000
#define NB 16
#define H 128
#define HINP 300
#define VOCAB 15000
#define NTOPIC 50

typedef __hip_bfloat16 bf16;
typedef __attribute__((ext_vector_type(8))) short bf16x8v;
typedef __attribute__((ext_vector_type(4))) float f32x4;

// per-etype CSR-build parameters
struct Et {
    const int* src; const int* dst; const float* w; const int* remap;
    int* cnt; int* off; int* bktcur; int* bkbase; uint2* scratch; uint2* cs;
    int E, lg, nbkt, stride, ndst;
};

#define EPB 2048  // edges per F1 block

// ==================== device helpers ====================
__device__ inline int wave_incl_scan(int v) {
    for (int off = 1; off < 64; off <<= 1) {
        int t = __shfl_up(v, off);
        if ((threadIdx.x & 63) >= off) v += t;
    }
    return v;
}

__device__ inline void mm128_dev(const float* A, const float* B, float* C, int lb) {
    int tid = lb * 256 + threadIdx.x;
    int i = tid >> 7, j = tid & 127;
    float acc = 0.f;
#pragma unroll 8
    for (int k = 0; k < 128; k++) acc += A[i * 128 + k] * B[k * 128 + j];
    C[tid] = acc;
}

__device__ inline void vecmat_half(const float* v, const float* M, const float* add, float* out) {
    int j = threadIdx.x & 127;
    float acc = add ? add[j] : 0.f;
    for (int k = 0; k < 128; k++) acc += v[k] * M[k * 128 + j];
    out[j] = acc;
}

__device__ inline short bfs(float f) {
    bf16 b = __float2bfloat16(f);
    return *reinterpret_cast<short*>(&b);
}

// 8 bf16 (uint4) * w -> 8 fp32 FMAs
__device__ inline void fma8(uint4 t, unsigned wb,
                            float& a0, float& a1, float& a2, float& a3,
                            float& a4, float& a5, float& a6, float& a7, float& aw) {
    float w = __uint_as_float(wb);
    a0 = fmaf(__uint_as_float(t.x << 16), w, a0);
    a1 = fmaf(__uint_as_float(t.x & 0xffff0000u), w, a1);
    a2 = fmaf(__uint_as_float(t.y << 16), w, a2);
    a3 = fmaf(__uint_as_float(t.y & 0xffff0000u), w, a3);
    a4 = fmaf(__uint_as_float(t.z << 16), w, a4);
    a5 = fmaf(__uint_as_float(t.z & 0xffff0000u), w, a5);
    a6 = fmaf(__uint_as_float(t.w << 16), w, a6);
    a7 = fmaf(__uint_as_float(t.w & 0xffff0000u), w, a7);
    aw += w;
}

__device__ inline unsigned pk2(float f0, float f1) {
    bf16 b0 = __float2bfloat16(f0), b1 = __float2bfloat16(f1);
    unsigned short s0 = *reinterpret_cast<unsigned short*>(&b0);
    unsigned short s1 = *reinterpret_cast<unsigned short*>(&b1);
    return ((unsigned)s1 << 16) | s0;
}

// software-pipelined 4-batch gather; 16-lane groups, uint4 (16B) loads; p.x pre-scaled src*16
// DEPTH 4 is the measured optimum: depth-8 doubled the live gather working set and
// collapsed L2 residency of the gather table (R7: aggBdoc 42->74us, FETCH 60->112MB).
__device__ inline void gpipe16(const uint4* __restrict__ t16, const uint2* __restrict__ csr,
                               int e, int e1, int st, int col,
                               float& a0, float& a1, float& a2, float& a3,
                               float& a4, float& a5, float& a6, float& a7, float& aw) {
    if (e + 3 * st < e1) {
        uint2 p0 = csr[e], p1 = csr[e + st], p2 = csr[e + 2 * st], p3 = csr[e + 3 * st];
        e += 4 * st;
        while (e + 3 * st < e1) {
            uint4 t0 = t16[p0.x + col], t1 = t16[p1.x + col];
            uint4 t2 = t16[p2.x + col], t3 = t16[p3.x + col];
            uint2 q0 = csr[e], q1 = csr[e + st], q2 = csr[e + 2 * st], q3 = csr[e + 3 * st];
            fma8(t0, p0.y, a0, a1, a2, a3, a4, a5, a6, a7, aw);
            fma8(t1, p1.y, a0, a1, a2, a3, a4, a5, a6, a7, aw);
            fma8(t2, p2.y, a0, a1, a2, a3, a4, a5, a6, a7, aw);
            fma8(t3, p3.y, a0, a1, a2, a3, a4, a5, a6, a7, aw);
            p0 = q0; p1 = q1; p2 = q2; p3 = q3;
            e += 4 * st;
        }
        uint4 t0 = t16[p0.x + col], t1 = t16[p1.x + col];
        uint4 t2 = t16[p2.x + col], t3 = t16[p3.x + col];
        fma8(t0, p0.y, a0, a1, a2, a3, a4, a5, a6, a7, aw);
        fma8(t1, p1.y, a0, a1, a2, a3, a4, a5, a6, a7, aw);
        fma8(t2, p2.y, a0, a1, a2, a3, a4, a5, a6, a7, aw);
        fma8(t3, p3.y, a0, a1, a2, a3, a4, a5, a6, a7, aw);
    }
    for (; e < e1; e += st) {
        uint2 p = csr[e];
        uint4 t = t16[p.x + col];
        fma8(t, p.y, a0, a1, a2, a3, a4, a5, a6, a7, aw);
    }
}

// ==================== K1: F1 bin pass (vectorized, 2048 edges/block) | prep level-1 ====================
__device__ inline void f1_run(const Et& a, int blk) {
    __shared__ int cnt[256], base[256];
    int e0 = blk * EPB;
    for (int i = threadIdx.x; i < a.nbkt; i += 256) cnt[i] = 0;
    __syncthreads();
    // phase A: vector-load dst (kept in regs), LDS histogram
    int4 d4[2];
#pragma unroll
    for (int c = 0; c < 2; c++) {
        int e = e0 + c * 1024 + threadIdx.x * 4;
        int4 d;
        if (e + 3 < a.E) {
            d = *reinterpret_cast<const int4*>(&a.dst[e]);
        } else {
            d.x = (e < a.E) ? a.dst[e] : -1;
            d.y = (e + 1 < a.E) ? a.dst[e + 1] : -1;
            d.z = (e + 2 < a.E) ? a.dst[e + 2] : -1;
            d.w = (e + 3 < a.E) ? a.dst[e + 3] : -1;
        }
        d4[c] = d;
        if (d.x >= 0) atomicAdd(&cnt[d.x >> a.lg], 1);
        if (d.y >= 0) atomicAdd(&cnt[d.y >> a.lg], 1);
        if (d.z >= 0) atomicAdd(&cnt[d.z >> a.lg], 1);
        if (d.w >= 0) atomicAdd(&cnt[d.w >> a.lg], 1);
    }
    __syncthreads();
    for (int i = threadIdx.x; i < a.nbkt; i += 256)
        base[i] = cnt[i] ? atomicAdd(&a.bktcur[i], cnt[i]) : 0;
    __syncthreads();
    for (int i = threadIdx.x; i < a.nbkt; i += 256) cnt[i] = base[i];
    __syncthreads();
    // phase B: vector-load src/w, remap-gather, scatter
    unsigned msk = (1u << a.lg) - 1;
#pragma unroll
    for (int c = 0; c < 2; c++) {
        int e = e0 + c * 1024 + threadIdx.x * 4;
        int4 d = d4[c];
        int4 s4;
        float4 w4;
        if (e + 3 < a.E) {
            s4 = *reinterpret_cast<const int4*>(&a.src[e]);
            w4 = *reinterpret_cast<const float4*>(&a.w[e]);
        } else {
            s4.x = (e < a.E) ? a.src[e] : 0;
            s4.y = (e + 1 < a.E) ? a.src[e + 1] : 0;
            s4.z = (e + 2 < a.E) ? a.src[e + 2] : 0;
            s4.w = (e + 3 < a.E) ? a.src[e + 3] : 0;
            w4.x = (e < a.E) ? a.w[e] : 0.f;
            w4.y = (e + 1 < a.E) ? a.w[e + 1] : 0.f;
            w4.z = (e + 2 < a.E) ? a.w[e + 2] : 0.f;
            w4.w = (e + 3 < a.E) ? a.w[e + 3] : 0.f;
        }
        if (a.remap) {
            if (d.x >= 0) s4.x = a.remap[s4.x];
            if (d.y >= 0) s4.y = a.remap[s4.y];
            if (d.z >= 0) s4.z = a.remap[s4.z];
            if (d.w >= 0) s4.w = a.remap[s4.w];
        }
        {
            int dd = d.x;
            if (dd >= 0) {
                int bb = dd >> a.lg;
                int p = atomicAdd(&cnt[bb], 1);
                if (p < a.stride)
                    a.scratch[(size_t)bb * a.stride + p] =
                        make_uint2((unsigned)s4.x | (((unsigned)dd & msk) << 17), __float_as_uint(w4.x));
            }
        }
        {
            int dd = d.y;
            if (dd >= 0) {
                int bb = dd >> a.lg;
                int p = atomicAdd(&cnt[bb], 1);
                if (p < a.stride)
                    a.scratch[(size_t)bb * a.stride + p] =
                        make_uint2((unsigned)s4.y | (((unsigned)dd & msk) << 17), __float_as_uint(w4.y));
            }
        }
        {
            int dd = d.z;
            if (dd >= 0) {
                int bb = dd >> a.lg;
                int p = atomicAdd(&cnt[bb], 1);
                if (p < a.stride)
                    a.scratch[(size_t)bb * a.stride + p] =
                        make_uint2((unsigned)s4.z | (((unsigned)dd & msk) << 17), __float_as_uint(w4.z));
            }
        }
        {
            int dd = d.w;
            if (dd >= 0) {
                int bb = dd >> a.lg;
                int p = atomicAdd(&cnt[bb], 1);
                if (p < a.stride)
                    a.scratch[(size_t)bb * a.stride + p] =
                        make_uint2((unsigned)s4.w | (((unsigned)dd & msk) << 17), __float_as_uint(w4.w));
            }
        }
    }
}

__global__ void k1_kernel(Et a0, Et a1, Et a2, Et a3, Et a4,
                          int f0, int f1b, int f2b, int f3b, int f4b,
                          const float* W1, const float* b1, const float* W2, const float* b2,
                          const float* Wa, const float* ba,
                          float* U1, float* V1, float* A_t1, float* X2, float* A_t2,
                          float* t1, float* u, float* t2, float* b_t1, float* b_t2) {
    int b = blockIdx.x;
    if (b < f0) f1_run(a0, b);
    else if (b < f1b) f1_run(a1, b - f0);
    else if (b < f2b) f1_run(a2, b - f1b);
    else if (b < f3b) f1_run(a3, b - f2b);
    else if (b < f4b) f1_run(a4, b - f3b);
    else {
        int pb = b - f4b;
        if (pb < 150) mm128_dev(Wa, W1, U1, pb);                                    // U1 = Wa@W1_0
        else if (pb < 214) mm128_dev(W1 + 16384, W1 + 2 * 16384, V1, pb - 150);     // V1 = W1_1@W1_2
        else if (pb < 278) mm128_dev(W1 + 3 * 16384, W1 + 4 * 16384, A_t1, pb - 214);
        else if (pb < 342) mm128_dev(W2, W2 + 16384, X2, pb - 278);                 // X2 = W2_0@W2_1
        else if (pb < 406) mm128_dev(W2 + 3 * 16384, W2 + 4 * 16384, A_t2, pb - 342);
        else if (pb == 406) {
            if (threadIdx.x < 128) vecmat_half(b1, W1 + 16384, b1 + 128, t1);       // t1
            else vecmat_half(ba, W1, nullptr, u);                                   // u = ba@W1_0
        } else if (pb == 407) {
            if (threadIdx.x < 128) vecmat_half(b1 + 3 * 128, W1 + 4 * 16384, b1 + 4 * 128, b_t1);
            else vecmat_half(b2, W2 + 16384, b2 + 128, t2);                         // t2
        } else {
            if (threadIdx.x < 128) vecmat_half(b2 + 3 * 128, W2 + 4 * 16384, b2 + 4 * 128, b_t2);
        }
    }
}

// ==================== K2: bucket scans | prep level-2 ====================
__device__ inline void bkscan_run(const Et& a) {
    __shared__ int wsum[4];
    int i = threadIdx.x;
    int v = (i < a.nbkt) ? min(a.bktcur[i], a.stride) : 0;
    int incl = wave_incl_scan(v);
    int wv = i >> 6;
    if ((i & 63) == 63) wsum[wv] = incl;
    __syncthreads();
    int base = 0;
    for (int k = 0; k < wv; k++) base += wsum[k];
    if (i < a.nbkt) a.bkbase[i] = incl + base - v;
}

__global__ void k2_kernel(Et a0, Et a1, Et a2, Et a3, Et a4,
                          const float* W1, const float* b1, const float* W2, const float* b2,
                          const float* U1, const float* V1, const float* X2,
                          const float* t1, const float* u, const float* t2,
                          bf16* P1t, float* A_w2, float* bv1, float* b_w2) {
    int b = blockIdx.x;
    if (b == 0) bkscan_run(a0);
    else if (b == 1) bkscan_run(a1);
    else if (b == 2) bkscan_run(a2);
    else if (b == 3) bkscan_run(a3);
    else if (b == 4) bkscan_run(a4);
    else {
        int pb = b - 5;
        if (pb < 160) {
            // P1 = U1@V1, stored TRANSPOSED bf16 [128][320]; rows 300..319 zeroed here
            int tid = pb * 256 + threadIdx.x;
            int i = tid >> 7, j = tid & 127;   // i in [0,320)
            float acc = 0.f;
            if (i < 300) {
#pragma unroll 8
                for (int k = 0; k < 128; k++) acc += U1[i * 128 + k] * V1[k * 128 + j];
            }
            P1t[(size_t)j * 320 + i] = __float2bfloat16(acc);
        } else if (pb < 224) {
            mm128_dev(X2, W2 + 2 * 16384, A_w2, pb - 160);                          // A_w2 = X2@W2_2
        } else {
            int j = threadIdx.x & 127;
            if (threadIdx.x < 128) {
                float acc = b1[2 * 128 + j];
                for (int k = 0; k < 128; k++)
                    acc += u[k] * V1[k * 128 + j] + t1[k] * W1[2 * 16384 + k * 128 + j];
                bv1[j] = acc;
            } else {
                float acc = b2[2 * 128 + j];
                for (int k = 0; k < 128; k++) acc += t2[k] * W2[2 * 16384 + k * 128 + j];
                b_w2[j] = acc;
            }
        }
    }
}

// ==================== K3: pv (MFMA) | pt | F2 CSR pass ====================
__device__ inline void f2_run(const Et& a, int blk, int* lhist, int* lcur, int* wsc) {
    int d0 = blk << a.lg;
    int nd = min(1 << a.lg, a.ndst - d0);
    int nE = min(a.bktcur[blk], a.stride);
    int base = a.bkbase[blk];
    const uint2* sc = a.scratch + (size_t)blk * a.stride;
    for (int i = threadIdx.x; i < nd; i += 256) lhist[i] = 0;
    __syncthreads();
    for (int e = threadIdx.x; e < nE; e += 256) atomicAdd(&lhist[sc[e].x >> 17], 1);
    __syncthreads();
    int per = (nd + 255) >> 8;
    int i0 = threadIdx.x * per;
    int s = 0;
    for (int k = 0; k < per; k++) {
        int i = i0 + k;
        if (i < nd) s += lhist[i];
    }
    int incl = wave_incl_scan(s);
    int wv = threadIdx.x >> 6;
    if ((threadIdx.x & 63) == 63) wsc[wv] = incl;
    __syncthreads();
    int wbase = 0;
    for (int k = 0; k < wv; k++) wbase += wsc[k];
    int run = wbase + incl - s;
    for (int k = 0; k < per; k++) {
        int i = i0 + k;
        if (i < nd) {
            int c = lhist[i];
            lcur[i] = run;
            a.cnt[d0 + i] = c;
            a.off[d0 + i] = base + run;
            run += c;
        }
    }
    __syncthreads();
    for (int e = threadIdx.x; e < nE; e += 256) {
        uint2 v = sc[e];
        int dl = v.x >> 17;
        int p = atomicAdd(&lcur[dl], 1);
        a.cs[base + p] = make_uint2((v.x & 0x1FFFFu) * 16u, v.y);  // pre-scaled src*16 (uint4 units)
    }
}

#define NBPVM 235  // ceil(VOCAB/64)
#define NBPT 25    // ceil(NTOPIC/2)

__global__ void k3_kernel(Et a0, Et a1, Et a2, Et a3, Et a4,
                          int g0, int g1, int g2, int g3, int g4,
                          const float* __restrict__ emb, const bf16* __restrict__ P1t,
                          const float* __restrict__ bv1, bf16* __restrict__ pv1,
                          const float* te, const float* A_t1, const float* b_t1, bf16* pt1) {
    __shared__ int sh[1028];
    int b = blockIdx.x;
    if (b < NBPVM) {
        // ---- pv via MFMA: 64 rows/block, wave w -> rows w*16..w*16+15, all 128 cols ----
        int wv = threadIdx.x >> 6, lane = threadIdx.x & 63;
        int r16 = lane & 15, g16 = lane >> 4;  // fragment row / k-group
        int rowbase = b * 64 + wv * 16;
        int arow = rowbase + r16;
        bool rok = arow < VOCAB;
        const size_t embrow = (size_t)arow * HINP;
        f32x4 acc[8];
#pragma unroll
        for (int c = 0; c < 8; c++) acc[c] = (f32x4){0.f, 0.f, 0.f, 0.f};
#pragma unroll
        for (int s = 0; s < 10; s++) {
            int k0 = s * 32 + g16 * 8;
            bf16x8v af;
            if (rok && k0 + 8 <= HINP) {
                float4 lo = *reinterpret_cast<const float4*>(&emb[embrow + k0]);
                float4 hi = *reinterpret_cast<const float4*>(&emb[embrow + k0 + 4]);
                af[0] = bfs(lo.x); af[1] = bfs(lo.y); af[2] = bfs(lo.z); af[3] = bfs(lo.w);
                af[4] = bfs(hi.x); af[5] = bfs(hi.y); af[6] = bfs(hi.z); af[7] = bfs(hi.w);
            } else if (rok && k0 < HINP) {
#pragma unroll
                for (int j = 0; j < 8; j++)
                    af[j] = (k0 + j < HINP) ? bfs(emb[embrow + k0 + j]) : (short)0;
            } else {
#pragma unroll
                for (int j = 0; j < 8; j++) af[j] = 0;
            }
#pragma unroll
            for (int c = 0; c < 8; c++) {
                int col = c * 16 + r16;
                bf16x8v bf = *reinterpret_cast<const bf16x8v*>(&P1t[(size_t)col * 320 + s * 32 + g16 * 8]);
                acc[c] = __builtin_amdgcn_mfma_f32_16x16x32_bf16(af, bf, acc[c], 0, 0, 0);
            }
        }
        // epilogue: D col = lane&15, row = (lane>>4)*4 + reg  [m89-verified]
        int orow0 = rowbase + g16 * 4;
#pragma unroll
        for (int c = 0; c < 8; c++) {
            int col = c * 16 + r16;
            float bv = bv1[col];
#pragma unroll
            for (int r = 0; r < 4; r++) {
                int row = orow0 + r;
                if (row < VOCAB) pv1[(size_t)row * 128 + col] = __float2bfloat16(acc[c][r] + bv);
            }
        }
        return;
    }
    if (b < NBPVM + NBPT) {
        int half = threadIdx.x >> 7, j = threadIdx.x & 127;
        int r = (b - NBPVM) * 2 + half;
        if (r < NTOPIC) {
            float acc = b_t1[j];
            for (int k = 0; k < 128; k++) acc += te[r * 128 + k] * A_t1[k * 128 + j];
            pt1[r * 128 + j] = __float2bfloat16(acc);
        }
        return;
    }
    int fb = b - NBPVM - NBPT;
    int* lhist = sh;
    int* lcur = sh + 512;
    int* wsc = sh + 1024;
    if (fb < g0) f2_run(a0, fb, lhist, lcur, wsc);
    else if (fb < g1) f2_run(a1, fb - g0, lhist, lcur, wsc);
    else if (fb < g2) f2_run(a2, fb - g1, lhist, lcur, wsc);
    else if (fb < g3) f2_run(a3, fb - g2, lhist, lcur, wsc);
    else f2_run(a4, fb - g3, lhist, lcur, wsc);
}

#define RED2(x) { x += __shfl_down(x, 16); x += __shfl_down(x, 32); }
#define RED1(x) { x += __shfl_down(x, 16); }

// ==================== K4: layer-1 aggregation (16-lane groups, uint4 gathers) ====================
// word rows: 16 rows/block, one 16-lane group per row (proven optimum)
__global__ __launch_bounds__(256, 8)
void aggA_kernel(const uint4* __restrict__ pv16, const uint4* __restrict__ pt16,
                 const uint2* __restrict__ cs_ww, const int* __restrict__ off_ww,
                 const int* __restrict__ cnt_ww, uint4* __restrict__ hw16,
                 const uint2* __restrict__ cs_wt, const int* __restrict__ off_wt,
                 const int* __restrict__ cnt_wt,
                 const uint2* __restrict__ cs_tt, const int* __restrict__ off_tt,
                 const int* __restrict__ cnt_tt, uint4* __restrict__ ht16) {
    __shared__ float redA[4][16][8], redC[4][16][8];
    int b = blockIdx.x;
    int wv = threadIdx.x >> 6;
    int lane = threadIdx.x & 63;
    int col = threadIdx.x & 15;
    if (b >= NT) {
        // word rows: 16 rows/block, one 16-lane group per row
        int row = (b - NT) * 16 + (threadIdx.x >> 4);
        int e = off_ww[row], n = cnt_ww[row];
        float a0 = 0.f, a1 = 0.f, a2 = 0.f, a3 = 0.f;
        float a4 = 0.f, a5 = 0.f, a6 = 0.f, a7 = 0.f, aw = 0.f;
        gpipe16(pv16, cs_ww, e, e + n, 1, col, a0, a1, a2, a3, a4, a5, a6, a7, aw);
        float inv = 1.f / fmaxf((float)n, 1.f);
        uint4 o;
        o.x = pk2(fmaxf(a0 * inv, 0.f), fmaxf(a1 * inv, 0.f));
        o.y = pk2(fmaxf(a2 * inv, 0.f), fmaxf(a3 * inv, 0.f));
        o.z = pk2(fmaxf(a4 * inv, 0.f), fmaxf(a5 * inv, 0.f));
        o.w = pk2(fmaxf(a6 * inv, 0.f), fmaxf(a7 * inv, 0.f));
        hw16[(size_t)row * 16 + col] = o;
        return;
    }
    // topic row: one row per block, 16 substreams (one per 16-lane group)
    int row = b;
    int g = threadIdx.x >> 4;
    int e0 = off_wt[row], n1 = cnt_wt[row];
    float a0 = 0.f, a1 = 0.f, a2 = 0.f, a3 = 0.f;
    float a4 = 0.f, a5 = 0.f, a6 = 0.f, a7 = 0.f, aw = 0.f;
    gpipe16(pv16, cs_wt, e0 + g, e0 + n1, 16, col, a0, a1, a2, a3, a4, a5, a6, a7, aw);
    int f0 = off_tt[row], n2 = cnt_tt[row];
    float c0 = 0.f, c1 = 0.f, c2 = 0.f, c3 = 0.f;
    float c4 = 0.f, c5 = 0.f, c6 = 0.f, c7 = 0.f, cw = 0.f;
    gpipe16(pt16, cs_tt, f0 + g, f0 + n2, 16, col, c0, c1, c2, c3, c4, c5, c6, c7, cw);
    RED2(a0); RED2(a1); RED2(a2); RED2(a3); RED2(a4); RED2(a5); RED2(a6); RED2(a7);
    RED2(c0); RED2(c1); RED2(c2); RED2(c3); RED2(c4); RED2(c5); RED2(c6); RED2(c7);
    if (lane < 16) {
        redA[wv][col][0] = a0; redA[wv][col][1] = a1; redA[wv][col][2] = a2; redA[wv][col][3] = a3;
        redA[wv][col][4] = a4; redA[wv][col][5] = a5; redA[wv][col][6] = a6; redA[wv][col][7] = a7;
        redC[wv][col][0] = c0; redC[wv][col][1] = c1; redC[wv][col][2] = c2; redC[wv][col][3] = c3;
        redC[wv][col][4] = c4; redC[wv][col][5] = c5; redC[wv][col][6] = c6; redC[wv][col][7] = c7;
    }
    __syncthreads();
    if (threadIdx.x < 16) {
        float A[8], C[8];
#pragma unroll
        for (int d = 0; d < 8; d++) { A[d] = redA[0][col][d]; C[d] = redC[0][col][d]; }
#pragma unroll
        for (int k = 1; k < 4; k++)
#pragma unroll
            for (int d = 0; d < 8; d++) { A[d] += redA[k][col][d]; C[d] += redC[k][col][d]; }
        float i1 = 1.f / fmaxf((float)n1, 1.f);
        float i2 = 1.f / fmaxf((float)n2, 1.f);
        uint4 o;
        o.x = pk2(fmaxf(A[0] * i1 + C[0] * i2, 0.f), fmaxf(A[1] * i1 + C[1] * i2, 0.f));
        o.y = pk2(fmaxf(A[2] * i1 + C[2] * i2, 0.f), fmaxf(A[3] * i1 + C[3] * i2, 0.f));
        o.z = pk2(fmaxf(A[4] * i1 + C[4] * i2, 0.f), fmaxf(A[5] * i1 + C[5] * i2, 0.f));
        o.w = pk2(fmaxf(A[6] * i1 + C[6] * i2, 0.f), fmaxf(A[7] * i1 + C[7] * i2, 0.f));
        ht16[(size_t)row * 16 + col] = o;
    }
}

// ==================== K5: fused layer-2 aggregation + doc projection ====================
// 8 docs/block, 2 substreams/doc (proven optimum)
__global__ __launch_bounds__(256, 8)
void aggBdoc_kernel(const uint4* __restrict__ hw16, const uint4* __restrict__ ht16,
                    const uint2* __restrict__ c_wd, const int* __restrict__ o_wd,
                    const int* __restrict__ n_wd,
                    const uint2* __restrict__ c_td, const int* __restrict__ o_td,
                    const int* __restrict__ n_td,
                    const float* __restrict__ A_w2, const float* __restrict__ b_w2,
                    const float* __restrict__ A_t2, const float* __restrict__ b_t2,
                    float* __restrict__ hd) {
    __shared__ float ld1[8][128], ld2[8][128];
    __shared__ float swc[8][4];
    int d0 = blockIdx.x * 8;
    int wv = threadIdx.x >> 6;
    int lane = threadIdx.x & 63;
    int col = threadIdx.x & 15;
    int lr = wv * 2 + (lane >> 5);     // doc 0..7 within block
    int sid = (lane >> 4) & 1;         // 2 substreams per doc
    int row = d0 + lr;
    {
        int e = o_wd[row], n = n_wd[row];
        float a0 = 0.f, a1 = 0.f, a2 = 0.f, a3 = 0.f;
        float a4 = 0.f, a5 = 0.f, a6 = 0.f, a7 = 0.f, aw = 0.f;
        gpipe16(hw16, c_wd, e + sid, e + n, 2, col, a0, a1, a2, a3, a4, a5, a6, a7, aw);
        RED1(a0); RED1(a1); RED1(a2); RED1(a3);
        RED1(a4); RED1(a5); RED1(a6); RED1(a7); RED1(aw);
        if ((lane & 31) < 16) {
            float* p = &ld1[lr][col * 8];
            p[0] = a0; p[1] = a1; p[2] = a2; p[3] = a3;
            p[4] = a4; p[5] = a5; p[6] = a6; p[7] = a7;
            if (col == 0) { swc[lr][0] = aw; swc[lr][1] = (float)n; }
        }
    }
    {
        int e = o_td[row], n = n_td[row];
        float a0 = 0.f, a1 = 0.f, a2 = 0.f, a3 = 0.f;
        float a4 = 0.f, a5 = 0.f, a6 = 0.f, a7 = 0.f, aw = 0.f;
        gpipe16(ht16, c_td, e + sid, e + n, 2, col, a0, a1, a2, a3, a4, a5, a6, a7, aw);
        RED1(a0); RED1(a1); RED1(a2); RED1(a3);
        RED1(a4); RED1(a5); RED1(a6); RED1(a7); RED1(aw);
        if ((lane & 31) < 16) {
            float* p = &ld2[lr][col * 8];
            p[0] = a0; p[1] = a1; p[2] = a2; p[3] = a3;
            p[4] = a4; p[5] = a5; p[6] = a6; p[7] = a7;
            if (col == 0) { swc[lr][2] = aw; swc[lr][3] = (float)n; }
        }
    }
    __syncthreads();
    int j = threadIdx.x & 127, hf = threadIdx.x >> 7;
    const float* L1 = &ld1[0][0];
    const float* L2 = &ld2[0][0];
    float a1v[4] = {0.f, 0.f, 0.f, 0.f}, a2v[4] = {0.f, 0.f, 0.f, 0.f};
    for (int k = 0; k < 128; k++) {
        float w1 = A_w2[k * 128 + j];
        float w2 = A_t2[k * 128 + j];
#pragma unroll
        for (int r = 0; r < 4; r++) {
            a1v[r] += L1[(hf * 4 + r) * 128 + k] * w1;
            a2v[r] += L2[(hf * 4 + r) * 128 + k] * w2;
        }
    }
    float bw = b_w2[j], bt = b_t2[j];
#pragma unroll
    for (int r = 0; r < 4; r++) {
        int rr = hf * 4 + r;
        float cc1 = fmaxf(swc[rr][1], 1.f), cc2 = fmaxf(swc[rr][3], 1.f);
        float v = (a1v[r] + bw * swc[rr][0]) / cc1 + (a2v[r] + bt * swc[rr][2]) / cc2;
        hd[(size_t)(d0 + rr) * 128 + j] = fmaxf(v, 0.f);
    }
}

// K6: doc pool — one block per graph
__global__ void docpool_kernel(const float* __restrict__ hd, const int* __restrict__ gid,
                               float* __restrict__ part) {
    __shared__ float red[8][128];
    int b = blockIdx.x;
    int r = threadIdx.x >> 7;
    int j = threadIdx.x & 127;
    const int DPG = ND / NB;
    int d0 = b * DPG, d1 = d0 + DPG;
    float m = -INFINITY;
    for (int d = d0 + r; d < d1; d += 8) {
        if (gid[d] == b) m = fmaxf(m, hd[(size_t)d * 128 + j]);
    }
    red[r][j] = m;
    __syncthreads();
    if (r == 0) {
#pragma unroll
        for (int k = 1; k < 8; k++) m = fmaxf(m, red[k][j]);
        part[b * 128 + j] = m;
    }
}

// K7: final: logits -> loss + sigmoid
__global__ void final_kernel(const float* __restrict__ part, const float* __restrict__ Wo,
                             const float* __restrict__ bo, const float* __restrict__ y,
                             float* __restrict__ out) {
    __shared__ float ls[16];
    int w = threadIdx.x >> 6, lane = threadIdx.x & 63;
    float m0 = part[(size_t)w * 128 + lane];
    float m1 = part[(size_t)w * 128 + 64 + lane];
    float p = m0 * Wo[lane] + m1 * Wo[64 + lane];
#pragma unroll
    for (int off = 32; off > 0; off >>= 1) p += __shfl_down(p, off);
    if (lane == 0) ls[w] = p + bo[0];
    __syncthreads();
    if (threadIdx.x < 16) {
        float l = ls[threadIdx.x];
        out[1 + threadIdx.x] = 1.f / (1.f + expf(-l));
    }
    if (threadIdx.x == 0) {
        float s = 0.f;
        for (int b = 0; b < 16; b++) {
            float l = ls[b];
            s += fmaxf(l, 0.f) - l * y[b] + log1pf(expf(-fabsf(l)));
        }
        out[0] = s / 16.f;
    }
}

extern "C" void kernel_launch(void* const* d_in, const int* in_sizes, int n_in,
                              void* d_out, int out_size, void* d_ws, size_t ws_size,
                              hipStream_t stream) {
    const int* word_ids = (const int*)d_in[0];
    const int* topic_ids = (const int*)d_in[1];
    const int* doc_graph_id = (const int*)d_in[2];
    const int* ww_src = (const int*)d_in[3];
    const int* ww_dst = (const int*)d_in[4];
    const float* ww_w = (const float*)d_in[5];
    const int* wt_src = (const int*)d_in[6];
    const int* wt_dst = (const int*)d_in[7];
    const float* wt_w = (const float*)d_in[8];
    const int* wd_src = (const int*)d_in[9];
    const int* wd_dst = (const int*)d_in[10];
    const float* wd_w = (const float*)d_in[11];
    const int* td_src = (const int*)d_in[12];
    const int* td_dst = (const int*)d_in[13];
    const float* td_w = (const float*)d_in[14];
    const int* tt_src = (const int*)d_in[15];
    const int* tt_dst = (const int*)d_in[16];
    const float* tt_w = (const float*)d_in[17];
    const float* word_embeds = (const float*)d_in[18];
    const float* topic_embeds = (const float*)d_in[19];
    const float* W_adapt = (const float*)d_in[20];
    const float* b_adapt = (const float*)d_in[21];
    const float* W1 = (const float*)d_in[22];
    const float* b1 = (const float*)d_in[23];
    const float* W2 = (const float*)d_in[24];
    const float* b2 = (const float*)d_in[25];
    const float* W_out = (const float*)d_in[26];
    const float* b_out = (const float*)d_in[27];
    const float* y_data = (const float*)d_in[28];
    float* out = (float*)d_out;

    const int E_ww = in_sizes[3], E_wt = in_sizes[6], E_wd = in_sizes[9];
    const int E_td = in_sizes[12], E_tt = in_sizes[15];

    // bucket configs: {lg, nbkt, stride}
    const int LG_WW = 9, NBK_WW = 196, ST_WW = 6144;
    const int LG_WT = 4, NBK_WT = 50,  ST_WT = 6656;
    const int LG_TT = 6, NBK_TT = 13,  ST_TT = 3712;
    const int LG_WD = 6, NBK_WD = 125, ST_WD = 4608;
    const int LG_TD = 8, NBK_TD = 32,  ST_TD = 3712;

    // -------- workspace --------
    float* ws = (float*)d_ws;
    size_t o = 0;
    auto alloc = [&](size_t n) { float* p = ws + o; o += (n + 63) & ~(size_t)63; return p; };
    bf16* pv1 = (bf16*)alloc((size_t)VOCAB * 64);
    bf16* pt1 = (bf16*)alloc((size_t)NTOPIC * 64);
    bf16* hw1 = (bf16*)alloc((size_t)NW * 64);
    bf16* ht1 = (bf16*)alloc((size_t)NT * 64);
    float* hd = alloc((size_t)ND * 128);
    // zeroed region: bucket cursors only (P1t pad zeroed in k2)
    int* bk_ww = (int*)alloc(NBK_WW);
    int* bk_wt = (int*)alloc(NBK_WT);
    int* bk_tt = (int*)alloc(NBK_TT);
    int* bk_wd = (int*)alloc(NBK_WD);
    int* bk_td = (int*)alloc(NBK_TD);
    float* zero_end = ws + o;
    bf16* P1t = (bf16*)alloc(128 * 320 / 2);   // bf16 [128][320]
    int* bkb_ww = (int*)alloc(NBK_WW);
    int* bkb_wt = (int*)alloc(NBK_WT);
    int* bkb_tt = (int*)alloc(NBK_TT);
    int* bkb_wd = (int*)alloc(NBK_WD);
    int* bkb_td = (int*)alloc(NBK_TD);
    int* cnt_ww = (int*)alloc(NW);
    int* cnt_wt = (int*)alloc(NT);
    int* cnt_tt = (int*)alloc(NT);
    int* cnt_wd = (int*)alloc(ND);
    int* cnt_td = (int*)alloc(ND);
    int* off_ww = (int*)alloc(NW);
    int* off_wt = (int*)alloc(NT);
    int* off_tt = (int*)alloc(NT);
    int* off_wd = (int*)alloc(ND);
    int* off_td = (int*)alloc(ND);
    uint2* cs_ww = (uint2*)alloc((size_t)E_ww * 2);
    uint2* cs_wt = (uint2*)alloc((size_t)E_wt * 2);
    uint2* cs_tt = (uint2*)alloc((size_t)E_tt * 2);
    uint2* cs_wd = (uint2*)alloc((size_t)E_wd * 2);
    uint2* cs_td = (uint2*)alloc((size_t)E_td * 2);
    uint2* sc_ww = (uint2*)alloc((size_t)NBK_WW * ST_WW * 2);
    uint2* sc_wt = (uint2*)alloc((size_t)NBK_WT * ST_WT * 2);
    uint2* sc_tt = (uint2*)alloc((size_t)NBK_TT * ST_TT * 2);
    uint2* sc_wd = (uint2*)alloc((size_t)NBK_WD * ST_WD * 2);
    uint2* sc_td = (uint2*)alloc((size_t)NBK_TD * ST_TD * 2);
    float* U1 = alloc(HINP * 128);
    float* V1 = alloc(128 * 128);
    float* X2 = alloc(128 * 128);
    float* A_t1 = alloc(128 * 128);
    float* A_w2 = alloc(128 * 128);
    float* A_t2 = alloc(128 * 128);
    float* t1v = alloc(128);
    float* uv = alloc(128);
    float* t2v = alloc(128);
    float* b_t1 = alloc(128);
    float* b_t2 = alloc(128);
    float* bv1 = alloc(128);
    float* b_w2 = alloc(128);
    float* part = alloc((size_t)NB * 128);
    (void)ws_size; (void)n_in; (void)out_size;

    Et eww = {ww_src, ww_dst, ww_w, word_ids,  cnt_ww, off_ww, bk_ww, bkb_ww, sc_ww, cs_ww, E_ww, LG_WW, NBK_WW, ST_WW, NW};
    Et ewt = {wt_src, wt_dst, wt_w, word_ids,  cnt_wt, off_wt, bk_wt, bkb_wt, sc_wt, cs_wt, E_wt, LG_WT, NBK_WT, ST_WT, NT};
    Et ett = {tt_src, tt_dst, tt_w, topic_ids, cnt_tt, off_tt, bk_tt, bkb_tt, sc_tt, cs_tt, E_tt, LG_TT, NBK_TT, ST_TT, NT};
    Et ewd = {wd_src, wd_dst, wd_w, nullptr,   cnt_wd, off_wd, bk_wd, bkb_wd, sc_wd, cs_wd, E_wd, LG_WD, NBK_WD, ST_WD, ND};
    Et etd = {td_src, td_dst, td_w, nullptr,   cnt_td, off_td, bk_td, bkb_td, sc_td, cs_td, E_td, LG_TD, NBK_TD, ST_TD, ND};

    // -------- memset bucket cursors (2.3 KB only) --------
    hipMemsetAsync(bk_ww, 0, (char*)zero_end - (char*)bk_ww, stream);

    // -------- K1: F1 (2048 edges/block, vectorized) | prep level-1 --------
    int f0 = (E_ww + EPB - 1) / EPB, f1b = f0 + (E_wt + EPB - 1) / EPB;
    int f2b = f1b + (E_tt + EPB - 1) / EPB, f3b = f2b + (E_wd + EPB - 1) / EPB;
    int f4b = f3b + (E_td + EPB - 1) / EPB;
    k1_kernel<<<f4b + 409, 256, 0, stream>>>(eww, ewt, ett, ewd, etd,
                                             f0, f1b, f2b, f3b, f4b,
                                             W1, b1, W2, b2, W_adapt, b_adapt,
                                             U1, V1, A_t1, X2, A_t2,
                                             t1v, uv, t2v, b_t1, b_t2);

    // -------- K2: bucket scans | prep level-2 (emits P1t bf16 transposed, incl. zero pad) --------
    k2_kernel<<<230, 256, 0, stream>>>(eww, ewt, ett, ewd, etd,
                                       W1, b1, W2, b2, U1, V1, X2, t1v, uv, t2v,
                                       P1t, A_w2, bv1, b_w2);

    // -------- K3: pv MFMA | pt | F2 CSR pass --------
    int g0 = NBK_WW, g1 = g0 + NBK_WT, g2 = g1 + NBK_TT, g3 = g2 + NBK_WD, g4 = g3 + NBK_TD;
    k3_kernel<<<NBPVM + NBPT + g4, 256, 0, stream>>>(
        eww, ewt, ett, ewd, etd, g0, g1, g2, g3, g4,
        word_embeds, P1t, bv1, pv1, topic_embeds, A_t1, b_t1, pt1);

    // -------- K4: layer-1 aggregation (topics first, then ww; 16 word rows/block) --------
    aggA_kernel<<<NT + NW / 16, 256, 0, stream>>>(
        (const uint4*)pv1, (const uint4*)pt1,
        cs_ww, off_ww, cnt_ww, (uint4*)hw1,
        cs_wt, off_wt, cnt_wt,
        cs_tt, off_tt, cnt_tt, (uint4*)ht1);

    // -------- K5: fused layer-2 aggregation + doc projection (8 docs/block) --------
    aggBdoc_kernel<<<ND / 8, 256, 0, stream>>>(
        (const uint4*)hw1, (const uint4*)ht1,
        cs_wd, off_wd, cnt_wd,
        cs_td, off_td, cnt_td,
        A_w2, b_w2, A_t2, b_t2, hd);

    // -------- readout --------
    docpool_kernel<<<NB, 1024, 0, stream>>>(hd, doc_graph_id, part);
    final_kernel<<<1, 1024, 0, stream>>>(part, W_out, b_out, y_data, out);
}

// Round 9
// 149.055 us; speedup vs baseline: 1.5506x; 1.2615x over previous
//
#include <hip/hip_runtime.h>
#include <hip/hip_bf16.h>
#include <math.h>

#define NW 100000
#define NT 800
#define ND 8000
#define NB 16
#define H 128
#define HINP 300
#define VOCAB 15000
#define NTOPIC 50

typedef __hip_bfloat16 bf16;
typedef __attribute__((ext_vector_type(8))) short bf16x8v;
typedef __attribute__((ext_vector_type(4))) float f32x4;

// per-etype CSR-build parameters
struct Et {
    const int* src; const int* dst; const float* w; const int* remap;
    int* cnt; int* off; int* bktcur; int* bkbase; uint2* scratch; uint2* cs;
    int E, lg, nbkt, stride, ndst;
};

#define EPB 2048  // edges per F1 block

// ==================== device helpers ====================
__device__ inline int wave_incl_scan(int v) {
    for (int off = 1; off < 64; off <<= 1) {
        int t = __shfl_up(v, off);
        if ((threadIdx.x & 63) >= off) v += t;
    }
    return v;
}

__device__ inline void mm128_dev(const float* A, const float* B, float* C, int lb) {
    int tid = lb * 256 + threadIdx.x;
    int i = tid >> 7, j = tid & 127;
    float acc = 0.f;
#pragma unroll 8
    for (int k = 0; k < 128; k++) acc += A[i * 128 + k] * B[k * 128 + j];
    C[tid] = acc;
}

__device__ inline void vecmat_half(const float* v, const float* M, const float* add, float* out) {
    int j = threadIdx.x & 127;
    float acc = add ? add[j] : 0.f;
    for (int k = 0; k < 128; k++) acc += v[k] * M[k * 128 + j];
    out[j] = acc;
}

__device__ inline short bfs(float f) {
    bf16 b = __float2bfloat16(f);
    return *reinterpret_cast<short*>(&b);
}

// 8 bf16 (uint4) * w -> 8 fp32 FMAs
__device__ inline void fma8(uint4 t, unsigned wb,
                            float& a0, float& a1, float& a2, float& a3,
                            float& a4, float& a5, float& a6, float& a7, float& aw) {
    float w = __uint_as_float(wb);
    a0 = fmaf(__uint_as_float(t.x << 16), w, a0);
    a1 = fmaf(__uint_as_float(t.x & 0xffff0000u), w, a1);
    a2 = fmaf(__uint_as_float(t.y << 16), w, a2);
    a3 = fmaf(__uint_as_float(t.y & 0xffff0000u), w, a3);
    a4 = fmaf(__uint_as_float(t.z << 16), w, a4);
    a5 = fmaf(__uint_as_float(t.z & 0xffff0000u), w, a5);
    a6 = fmaf(__uint_as_float(t.w << 16), w, a6);
    a7 = fmaf(__uint_as_float(t.w & 0xffff0000u), w, a7);
    aw += w;
}

__device__ inline unsigned pk2(float f0, float f1) {
    bf16 b0 = __float2bfloat16(f0), b1 = __float2bfloat16(f1);
    unsigned short s0 = *reinterpret_cast<unsigned short*>(&b0);
    unsigned short s1 = *reinterpret_cast<unsigned short*>(&b1);
    return ((unsigned)s1 << 16) | s0;
}

// software-pipelined 4-batch gather; 16-lane groups, uint4 (16B) loads; p.x pre-scaled src*16
// DEPTH 4 is the measured optimum: depth-8 doubled the live gather working set and
// collapsed L2 residency of the gather table (R7: aggBdoc 42->74us, FETCH 60->112MB).
__device__ inline void gpipe16(const uint4* __restrict__ t16, const uint2* __restrict__ csr,
                               int e, int e1, int st, int col,
                               float& a0, float& a1, float& a2, float& a3,
                               float& a4, float& a5, float& a6, float& a7, float& aw) {
    if (e + 3 * st < e1) {
        uint2 p0 = csr[e], p1 = csr[e + st], p2 = csr[e + 2 * st], p3 = csr[e + 3 * st];
        e += 4 * st;
        while (e + 3 * st < e1) {
            uint4 t0 = t16[p0.x + col], t1 = t16[p1.x + col];
            uint4 t2 = t16[p2.x + col], t3 = t16[p3.x + col];
            uint2 q0 = csr[e], q1 = csr[e + st], q2 = csr[e + 2 * st], q3 = csr[e + 3 * st];
            fma8(t0, p0.y, a0, a1, a2, a3, a4, a5, a6, a7, aw);
            fma8(t1, p1.y, a0, a1, a2, a3, a4, a5, a6, a7, aw);
            fma8(t2, p2.y, a0, a1, a2, a3, a4, a5, a6, a7, aw);
            fma8(t3, p3.y, a0, a1, a2, a3, a4, a5, a6, a7, aw);
            p0 = q0; p1 = q1; p2 = q2; p3 = q3;
            e += 4 * st;
        }
        uint4 t0 = t16[p0.x + col], t1 = t16[p1.x + col];
        uint4 t2 = t16[p2.x + col], t3 = t16[p3.x + col];
        fma8(t0, p0.y, a0, a1, a2, a3, a4, a5, a6, a7, aw);
        fma8(t1, p1.y, a0, a1, a2, a3, a4, a5, a6, a7, aw);
        fma8(t2, p2.y, a0, a1, a2, a3, a4, a5, a6, a7, aw);
        fma8(t3, p3.y, a0, a1, a2, a3, a4, a5, a6, a7, aw);
    }
    for (; e < e1; e += st) {
        uint2 p = csr[e];
        uint4 t = t16[p.x + col];
        fma8(t, p.y, a0, a1, a2, a3, a4, a5, a6, a7, aw);
    }
}

// ==================== K1: F1 bin pass (vectorized, 2048 edges/block) | prep level-1 ====================
__device__ inline void f1_run(const Et& a, int blk) {
    __shared__ int cnt[256], base[256];
    int e0 = blk * EPB;
    for (int i = threadIdx.x; i < a.nbkt; i += 256) cnt[i] = 0;
    __syncthreads();
    // phase A: vector-load dst (kept in regs), LDS histogram
    int4 d4[2];
#pragma unroll
    for (int c = 0; c < 2; c++) {
        int e = e0 + c * 1024 + threadIdx.x * 4;
        int4 d;
        if (e + 3 < a.E) {
            d = *reinterpret_cast<const int4*>(&a.dst[e]);
        } else {
            d.x = (e < a.E) ? a.dst[e] : -1;
            d.y = (e + 1 < a.E) ? a.dst[e + 1] : -1;
            d.z = (e + 2 < a.E) ? a.dst[e + 2] : -1;
            d.w = (e + 3 < a.E) ? a.dst[e + 3] : -1;
        }
        d4[c] = d;
        if (d.x >= 0) atomicAdd(&cnt[d.x >> a.lg], 1);
        if (d.y >= 0) atomicAdd(&cnt[d.y >> a.lg], 1);
        if (d.z >= 0) atomicAdd(&cnt[d.z >> a.lg], 1);
        if (d.w >= 0) atomicAdd(&cnt[d.w >> a.lg], 1);
    }
    __syncthreads();
    for (int i = threadIdx.x; i < a.nbkt; i += 256)
        base[i] = cnt[i] ? atomicAdd(&a.bktcur[i], cnt[i]) : 0;
    __syncthreads();
    for (int i = threadIdx.x; i < a.nbkt; i += 256) cnt[i] = base[i];
    __syncthreads();
    // phase B: vector-load src/w, remap-gather, scatter
    unsigned msk = (1u << a.lg) - 1;
#pragma unroll
    for (int c = 0; c < 2; c++) {
        int e = e0 + c * 1024 + threadIdx.x * 4;
        int4 d = d4[c];
        int4 s4;
        float4 w4;
        if (e + 3 < a.E) {
            s4 = *reinterpret_cast<const int4*>(&a.src[e]);
            w4 = *reinterpret_cast<const float4*>(&a.w[e]);
        } else {
            s4.x = (e < a.E) ? a.src[e] : 0;
            s4.y = (e + 1 < a.E) ? a.src[e + 1] : 0;
            s4.z = (e + 2 < a.E) ? a.src[e + 2] : 0;
            s4.w = (e + 3 < a.E) ? a.src[e + 3] : 0;
            w4.x = (e < a.E) ? a.w[e] : 0.f;
            w4.y = (e + 1 < a.E) ? a.w[e + 1] : 0.f;
            w4.z = (e + 2 < a.E) ? a.w[e + 2] : 0.f;
            w4.w = (e + 3 < a.E) ? a.w[e + 3] : 0.f;
        }
        if (a.remap) {
            if (d.x >= 0) s4.x = a.remap[s4.x];
            if (d.y >= 0) s4.y = a.remap[s4.y];
            if (d.z >= 0) s4.z = a.remap[s4.z];
            if (d.w >= 0) s4.w = a.remap[s4.w];
        }
        {
            int dd = d.x;
            if (dd >= 0) {
                int bb = dd >> a.lg;
                int p = atomicAdd(&cnt[bb], 1);
                if (p < a.stride)
                    a.scratch[(size_t)bb * a.stride + p] =
                        make_uint2((unsigned)s4.x | (((unsigned)dd & msk) << 17), __float_as_uint(w4.x));
            }
        }
        {
            int dd = d.y;
            if (dd >= 0) {
                int bb = dd >> a.lg;
                int p = atomicAdd(&cnt[bb], 1);
                if (p < a.stride)
                    a.scratch[(size_t)bb * a.stride + p] =
                        make_uint2((unsigned)s4.y | (((unsigned)dd & msk) << 17), __float_as_uint(w4.y));
            }
        }
        {
            int dd = d.z;
            if (dd >= 0) {
                int bb = dd >> a.lg;
                int p = atomicAdd(&cnt[bb], 1);
                if (p < a.stride)
                    a.scratch[(size_t)bb * a.stride + p] =
                        make_uint2((unsigned)s4.z | (((unsigned)dd & msk) << 17), __float_as_uint(w4.z));
            }
        }
        {
            int dd = d.w;
            if (dd >= 0) {
                int bb = dd >> a.lg;
                int p = atomicAdd(&cnt[bb], 1);
                if (p < a.stride)
                    a.scratch[(size_t)bb * a.stride + p] =
                        make_uint2((unsigned)s4.w | (((unsigned)dd & msk) << 17), __float_as_uint(w4.w));
            }
        }
    }
}

__global__ void k1_kernel(Et a0, Et a1, Et a2, Et a3, Et a4,
                          int f0, int f1b, int f2b, int f3b, int f4b,
                          const float* W1, const float* b1, const float* W2, const float* b2,
                          const float* Wa, const float* ba,
                          float* U1, float* V1, float* A_t1, float* X2, float* A_t2,
                          float* t1, float* u, float* t2, float* b_t1, float* b_t2) {
    int b = blockIdx.x;
    if (b < f0) f1_run(a0, b);
    else if (b < f1b) f1_run(a1, b - f0);
    else if (b < f2b) f1_run(a2, b - f1b);
    else if (b < f3b) f1_run(a3, b - f2b);
    else if (b < f4b) f1_run(a4, b - f3b);
    else {
        int pb = b - f4b;
        if (pb < 150) mm128_dev(Wa, W1, U1, pb);                                    // U1 = Wa@W1_0
        else if (pb < 214) mm128_dev(W1 + 16384, W1 + 2 * 16384, V1, pb - 150);     // V1 = W1_1@W1_2
        else if (pb < 278) mm128_dev(W1 + 3 * 16384, W1 + 4 * 16384, A_t1, pb - 214);
        else if (pb < 342) mm128_dev(W2, W2 + 16384, X2, pb - 278);                 // X2 = W2_0@W2_1
        else if (pb < 406) mm128_dev(W2 + 3 * 16384, W2 + 4 * 16384, A_t2, pb - 342);
        else if (pb == 406) {
            if (threadIdx.x < 128) vecmat_half(b1, W1 + 16384, b1 + 128, t1);       // t1
            else vecmat_half(ba, W1, nullptr, u);                                   // u = ba@W1_0
        } else if (pb == 407) {
            if (threadIdx.x < 128) vecmat_half(b1 + 3 * 128, W1 + 4 * 16384, b1 + 4 * 128, b_t1);
            else vecmat_half(b2, W2 + 16384, b2 + 128, t2);                         // t2
        } else {
            if (threadIdx.x < 128) vecmat_half(b2 + 3 * 128, W2 + 4 * 16384, b2 + 4 * 128, b_t2);
        }
    }
}

// ==================== K2: bucket scans | prep level-2 ====================
__device__ inline void bkscan_run(const Et& a) {
    __shared__ int wsum[4];
    int i = threadIdx.x;
    int v = (i < a.nbkt) ? min(a.bktcur[i], a.stride) : 0;
    int incl = wave_incl_scan(v);
    int wv = i >> 6;
    if ((i & 63) == 63) wsum[wv] = incl;
    __syncthreads();
    int base = 0;
    for (int k = 0; k < wv; k++) base += wsum[k];
    if (i < a.nbkt) a.bkbase[i] = incl + base - v;
}

__global__ void k2_kernel(Et a0, Et a1, Et a2, Et a3, Et a4,
                          const float* W1, const float* b1, const float* W2, const float* b2,
                          const float* U1, const float* V1, const float* X2,
                          const float* t1, const float* u, const float* t2,
                          bf16* P1t, float* A_w2, float* bv1, float* b_w2) {
    int b = blockIdx.x;
    if (b == 0) bkscan_run(a0);
    else if (b == 1) bkscan_run(a1);
    else if (b == 2) bkscan_run(a2);
    else if (b == 3) bkscan_run(a3);
    else if (b == 4) bkscan_run(a4);
    else {
        int pb = b - 5;
        if (pb < 160) {
            // P1 = U1@V1, stored TRANSPOSED bf16 [128][320]; rows 300..319 zeroed here
            int tid = pb * 256 + threadIdx.x;
            int i = tid >> 7, j = tid & 127;   // i in [0,320)
            float acc = 0.f;
            if (i < 300) {
#pragma unroll 8
                for (int k = 0; k < 128; k++) acc += U1[i * 128 + k] * V1[k * 128 + j];
            }
            P1t[(size_t)j * 320 + i] = __float2bfloat16(acc);
        } else if (pb < 224) {
            mm128_dev(X2, W2 + 2 * 16384, A_w2, pb - 160);                          // A_w2 = X2@W2_2
        } else {
            int j = threadIdx.x & 127;
            if (threadIdx.x < 128) {
                float acc = b1[2 * 128 + j];
                for (int k = 0; k < 128; k++)
                    acc += u[k] * V1[k * 128 + j] + t1[k] * W1[2 * 16384 + k * 128 + j];
                bv1[j] = acc;
            } else {
                float acc = b2[2 * 128 + j];
                for (int k = 0; k < 128; k++) acc += t2[k] * W2[2 * 16384 + k * 128 + j];
                b_w2[j] = acc;
            }
        }
    }
}

// ==================== K3: pv (MFMA) | pt | F2 CSR pass ====================
__device__ inline void f2_run(const Et& a, int blk, int* lhist, int* lcur, int* wsc) {
    int d0 = blk << a.lg;
    int nd = min(1 << a.lg, a.ndst - d0);
    int nE = min(a.bktcur[blk], a.stride);
    int base = a.bkbase[blk];
    const uint2* sc = a.scratch + (size_t)blk * a.stride;
    for (int i = threadIdx.x; i < nd; i += 256) lhist[i] = 0;
    __syncthreads();
    for (int e = threadIdx.x; e < nE; e += 256) atomicAdd(&lhist[sc[e].x >> 17], 1);
    __syncthreads();
    int per = (nd + 255) >> 8;
    int i0 = threadIdx.x * per;
    int s = 0;
    for (int k = 0; k < per; k++) {
        int i = i0 + k;
        if (i < nd) s += lhist[i];
    }
    int incl = wave_incl_scan(s);
    int wv = threadIdx.x >> 6;
    if ((threadIdx.x & 63) == 63) wsc[wv] = incl;
    __syncthreads();
    int wbase = 0;
    for (int k = 0; k < wv; k++) wbase += wsc[k];
    int run = wbase + incl - s;
    for (int k = 0; k < per; k++) {
        int i = i0 + k;
        if (i < nd) {
            int c = lhist[i];
            lcur[i] = run;
            a.cnt[d0 + i] = c;
            a.off[d0 + i] = base + run;
            run += c;
        }
    }
    __syncthreads();
    for (int e = threadIdx.x; e < nE; e += 256) {
        uint2 v = sc[e];
        int dl = v.x >> 17;
        int p = atomicAdd(&lcur[dl], 1);
        a.cs[base + p] = make_uint2((v.x & 0x1FFFFu) * 16u, v.y);  // pre-scaled src*16 (uint4 units)
    }
}

#define NBPVM 235  // ceil(VOCAB/64)
#define NBPT 25    // ceil(NTOPIC/2)

__global__ void k3_kernel(Et a0, Et a1, Et a2, Et a3, Et a4,
                          int g0, int g1, int g2, int g3, int g4,
                          const float* __restrict__ emb, const bf16* __restrict__ P1t,
                          const float* __restrict__ bv1, bf16* __restrict__ pv1,
                          const float* te, const float* A_t1, const float* b_t1, bf16* pt1) {
    __shared__ int sh[1028];
    int b = blockIdx.x;
    if (b < NBPVM) {
        // ---- pv via MFMA: 64 rows/block, wave w -> rows w*16..w*16+15, all 128 cols ----
        int wv = threadIdx.x >> 6, lane = threadIdx.x & 63;
        int r16 = lane & 15, g16 = lane >> 4;  // fragment row / k-group
        int rowbase = b * 64 + wv * 16;
        int arow = rowbase + r16;
        bool rok = arow < VOCAB;
        const size_t embrow = (size_t)arow * HINP;
        f32x4 acc[8];
#pragma unroll
        for (int c = 0; c < 8; c++) acc[c] = (f32x4){0.f, 0.f, 0.f, 0.f};
#pragma unroll
        for (int s = 0; s < 10; s++) {
            int k0 = s * 32 + g16 * 8;
            bf16x8v af;
            if (rok && k0 + 8 <= HINP) {
                float4 lo = *reinterpret_cast<const float4*>(&emb[embrow + k0]);
                float4 hi = *reinterpret_cast<const float4*>(&emb[embrow + k0 + 4]);
                af[0] = bfs(lo.x); af[1] = bfs(lo.y); af[2] = bfs(lo.z); af[3] = bfs(lo.w);
                af[4] = bfs(hi.x); af[5] = bfs(hi.y); af[6] = bfs(hi.z); af[7] = bfs(hi.w);
            } else if (rok && k0 < HINP) {
#pragma unroll
                for (int j = 0; j < 8; j++)
                    af[j] = (k0 + j < HINP) ? bfs(emb[embrow + k0 + j]) : (short)0;
            } else {
#pragma unroll
                for (int j = 0; j < 8; j++) af[j] = 0;
            }
#pragma unroll
            for (int c = 0; c < 8; c++) {
                int col = c * 16 + r16;
                bf16x8v bf = *reinterpret_cast<const bf16x8v*>(&P1t[(size_t)col * 320 + s * 32 + g16 * 8]);
                acc[c] = __builtin_amdgcn_mfma_f32_16x16x32_bf16(af, bf, acc[c], 0, 0, 0);
            }
        }
        // epilogue: D col = lane&15, row = (lane>>4)*4 + reg  [m89-verified]
        int orow0 = rowbase + g16 * 4;
#pragma unroll
        for (int c = 0; c < 8; c++) {
            int col = c * 16 + r16;
            float bv = bv1[col];
#pragma unroll
            for (int r = 0; r < 4; r++) {
                int row = orow0 + r;
                if (row < VOCAB) pv1[(size_t)row * 128 + col] = __float2bfloat16(acc[c][r] + bv);
            }
        }
        return;
    }
    if (b < NBPVM + NBPT) {
        int half = threadIdx.x >> 7, j = threadIdx.x & 127;
        int r = (b - NBPVM) * 2 + half;
        if (r < NTOPIC) {
            float acc = b_t1[j];
            for (int k = 0; k < 128; k++) acc += te[r * 128 + k] * A_t1[k * 128 + j];
            pt1[r * 128 + j] = __float2bfloat16(acc);
        }
        return;
    }
    int fb = b - NBPVM - NBPT;
    int* lhist = sh;
    int* lcur = sh + 512;
    int* wsc = sh + 1024;
    if (fb < g0) f2_run(a0, fb, lhist, lcur, wsc);
    else if (fb < g1) f2_run(a1, fb - g0, lhist, lcur, wsc);
    else if (fb < g2) f2_run(a2, fb - g1, lhist, lcur, wsc);
    else if (fb < g3) f2_run(a3, fb - g2, lhist, lcur, wsc);
    else f2_run(a4, fb - g3, lhist, lcur, wsc);
}

#define RED2(x) { x += __shfl_down(x, 16); x += __shfl_down(x, 32); }
#define RED1(x) { x += __shfl_down(x, 16); }

// ==================== K4: layer-1 aggregation (16-lane groups, uint4 gathers) ====================
// word rows: 16 rows/block, one 16-lane group per row (proven optimum)
__global__ __launch_bounds__(256, 8)
void aggA_kernel(const uint4* __restrict__ pv16, const uint4* __restrict__ pt16,
                 const uint2* __restrict__ cs_ww, const int* __restrict__ off_ww,
                 const int* __restrict__ cnt_ww, uint4* __restrict__ hw16,
                 const uint2* __restrict__ cs_wt, const int* __restrict__ off_wt,
                 const int* __restrict__ cnt_wt,
                 const uint2* __restrict__ cs_tt, const int* __restrict__ off_tt,
                 const int* __restrict__ cnt_tt, uint4* __restrict__ ht16) {
    __shared__ float redA[4][16][8], redC[4][16][8];
    int b = blockIdx.x;
    int wv = threadIdx.x >> 6;
    int lane = threadIdx.x & 63;
    int col = threadIdx.x & 15;
    if (b >= NT) {
        // word rows: 16 rows/block, one 16-lane group per row
        int row = (b - NT) * 16 + (threadIdx.x >> 4);
        int e = off_ww[row], n = cnt_ww[row];
        float a0 = 0.f, a1 = 0.f, a2 = 0.f, a3 = 0.f;
        float a4 = 0.f, a5 = 0.f, a6 = 0.f, a7 = 0.f, aw = 0.f;
        gpipe16(pv16, cs_ww, e, e + n, 1, col, a0, a1, a2, a3, a4, a5, a6, a7, aw);
        float inv = 1.f / fmaxf((float)n, 1.f);
        uint4 o;
        o.x = pk2(fmaxf(a0 * inv, 0.f), fmaxf(a1 * inv, 0.f));
        o.y = pk2(fmaxf(a2 * inv, 0.f), fmaxf(a3 * inv, 0.f));
        o.z = pk2(fmaxf(a4 * inv, 0.f), fmaxf(a5 * inv, 0.f));
        o.w = pk2(fmaxf(a6 * inv, 0.f), fmaxf(a7 * inv, 0.f));
        hw16[(size_t)row * 16 + col] = o;
        return;
    }
    // topic row: one row per block, 16 substreams (one per 16-lane group)
    int row = b;
    int g = threadIdx.x >> 4;
    int e0 = off_wt[row], n1 = cnt_wt[row];
    float a0 = 0.f, a1 = 0.f, a2 = 0.f, a3 = 0.f;
    float a4 = 0.f, a5 = 0.f, a6 = 0.f, a7 = 0.f, aw = 0.f;
    gpipe16(pv16, cs_wt, e0 + g, e0 + n1, 16, col, a0, a1, a2, a3, a4, a5, a6, a7, aw);
    int f0 = off_tt[row], n2 = cnt_tt[row];
    float c0 = 0.f, c1 = 0.f, c2 = 0.f, c3 = 0.f;
    float c4 = 0.f, c5 = 0.f, c6 = 0.f, c7 = 0.f, cw = 0.f;
    gpipe16(pt16, cs_tt, f0 + g, f0 + n2, 16, col, c0, c1, c2, c3, c4, c5, c6, c7, cw);
    RED2(a0); RED2(a1); RED2(a2); RED2(a3); RED2(a4); RED2(a5); RED2(a6); RED2(a7);
    RED2(c0); RED2(c1); RED2(c2); RED2(c3); RED2(c4); RED2(c5); RED2(c6); RED2(c7);
    if (lane < 16) {
        redA[wv][col][0] = a0; redA[wv][col][1] = a1; redA[wv][col][2] = a2; redA[wv][col][3] = a3;
        redA[wv][col][4] = a4; redA[wv][col][5] = a5; redA[wv][col][6] = a6; redA[wv][col][7] = a7;
        redC[wv][col][0] = c0; redC[wv][col][1] = c1; redC[wv][col][2] = c2; redC[wv][col][3] = c3;
        redC[wv][col][4] = c4; redC[wv][col][5] = c5; redC[wv][col][6] = c6; redC[wv][col][7] = c7;
    }
    __syncthreads();
    if (threadIdx.x < 16) {
        float A[8], C[8];
#pragma unroll
        for (int d = 0; d < 8; d++) { A[d] = redA[0][col][d]; C[d] = redC[0][col][d]; }
#pragma unroll
        for (int k = 1; k < 4; k++)
#pragma unroll
            for (int d = 0; d < 8; d++) { A[d] += redA[k][col][d]; C[d] += redC[k][col][d]; }
        float i1 = 1.f / fmaxf((float)n1, 1.f);
        float i2 = 1.f / fmaxf((float)n2, 1.f);
        uint4 o;
        o.x = pk2(fmaxf(A[0] * i1 + C[0] * i2, 0.f), fmaxf(A[1] * i1 + C[1] * i2, 0.f));
        o.y = pk2(fmaxf(A[2] * i1 + C[2] * i2, 0.f), fmaxf(A[3] * i1 + C[3] * i2, 0.f));
        o.z = pk2(fmaxf(A[4] * i1 + C[4] * i2, 0.f), fmaxf(A[5] * i1 + C[5] * i2, 0.f));
        o.w = pk2(fmaxf(A[6] * i1 + C[6] * i2, 0.f), fmaxf(A[7] * i1 + C[7] * i2, 0.f));
        ht16[(size_t)row * 16 + col] = o;
    }
}

// ==================== K5: fused layer-2 aggregation + doc projection + doc pool ====================
// 8 docs/block, 2 substreams/doc (proven optimum); doc max fused via atomicMax
// (hd values are post-ReLU >= 0, so float bits are monotonic -> uint atomicMax is
//  a correct float max; part is zero-initialized, 0 == identity for max of nonnegs)
__global__ __launch_bounds__(256, 8)
void aggBdoc_kernel(const uint4* __restrict__ hw16, const uint4* __restrict__ ht16,
                    const uint2* __restrict__ c_wd, const int* __restrict__ o_wd,
                    const int* __restrict__ n_wd,
                    const uint2* __restrict__ c_td, const int* __restrict__ o_td,
                    const int* __restrict__ n_td,
                    const float* __restrict__ A_w2, const float* __restrict__ b_w2,
                    const float* __restrict__ A_t2, const float* __restrict__ b_t2,
                    const int* __restrict__ gid, float* __restrict__ part) {
    __shared__ float ld1[8][128], ld2[8][128];
    __shared__ float swc[8][4];
    int d0 = blockIdx.x * 8;
    int wv = threadIdx.x >> 6;
    int lane = threadIdx.x & 63;
    int col = threadIdx.x & 15;
    int lr = wv * 2 + (lane >> 5);     // doc 0..7 within block
    int sid = (lane >> 4) & 1;         // 2 substreams per doc
    int row = d0 + lr;
    {
        int e = o_wd[row], n = n_wd[row];
        float a0 = 0.f, a1 = 0.f, a2 = 0.f, a3 = 0.f;
        float a4 = 0.f, a5 = 0.f, a6 = 0.f, a7 = 0.f, aw = 0.f;
        gpipe16(hw16, c_wd, e + sid, e + n, 2, col, a0, a1, a2, a3, a4, a5, a6, a7, aw);
        RED1(a0); RED1(a1); RED1(a2); RED1(a3);
        RED1(a4); RED1(a5); RED1(a6); RED1(a7); RED1(aw);
        if ((lane & 31) < 16) {
            float* p = &ld1[lr][col * 8];
            p[0] = a0; p[1] = a1; p[2] = a2; p[3] = a3;
            p[4] = a4; p[5] = a5; p[6] = a6; p[7] = a7;
            if (col == 0) { swc[lr][0] = aw; swc[lr][1] = (float)n; }
        }
    }
    {
        int e = o_td[row], n = n_td[row];
        float a0 = 0.f, a1 = 0.f, a2 = 0.f, a3 = 0.f;
        float a4 = 0.f, a5 = 0.f, a6 = 0.f, a7 = 0.f, aw = 0.f;
        gpipe16(ht16, c_td, e + sid, e + n, 2, col, a0, a1, a2, a3, a4, a5, a6, a7, aw);
        RED1(a0); RED1(a1); RED1(a2); RED1(a3);
        RED1(a4); RED1(a5); RED1(a6); RED1(a7); RED1(aw);
        if ((lane & 31) < 16) {
            float* p = &ld2[lr][col * 8];
            p[0] = a0; p[1] = a1; p[2] = a2; p[3] = a3;
            p[4] = a4; p[5] = a5; p[6] = a6; p[7] = a7;
            if (col == 0) { swc[lr][2] = aw; swc[lr][3] = (float)n; }
        }
    }
    __syncthreads();
    int j = threadIdx.x & 127, hf = threadIdx.x >> 7;
    const float* L1 = &ld1[0][0];
    const float* L2 = &ld2[0][0];
    float a1v[4] = {0.f, 0.f, 0.f, 0.f}, a2v[4] = {0.f, 0.f, 0.f, 0.f};
    for (int k = 0; k < 128; k++) {
        float w1 = A_w2[k * 128 + j];
        float w2 = A_t2[k * 128 + j];
#pragma unroll
        for (int r = 0; r < 4; r++) {
            a1v[r] += L1[(hf * 4 + r) * 128 + k] * w1;
            a2v[r] += L2[(hf * 4 + r) * 128 + k] * w2;
        }
    }
    float bw = b_w2[j], bt = b_t2[j];
    // fused doc pool: per-thread pre-max over its 4 docs grouped by graph id,
    // then one atomicMax per distinct graph (usually 1).
    float m = 0.f;
    int gprev = gid[d0 + hf * 4];
#pragma unroll
    for (int r = 0; r < 4; r++) {
        int rr = hf * 4 + r;
        float cc1 = fmaxf(swc[rr][1], 1.f), cc2 = fmaxf(swc[rr][3], 1.f);
        float v = (a1v[r] + bw * swc[rr][0]) / cc1 + (a2v[r] + bt * swc[rr][2]) / cc2;
        v = fmaxf(v, 0.f);
        int g = gid[d0 + rr];
        if (g != gprev) {
            atomicMax(reinterpret_cast<unsigned*>(&part[(size_t)gprev * 128 + j]),
                      __float_as_uint(m));
            m = 0.f;
            gprev = g;
        }
        m = fmaxf(m, v);
    }
    atomicMax(reinterpret_cast<unsigned*>(&part[(size_t)gprev * 128 + j]), __float_as_uint(m));
}

// K7: final: logits -> loss + sigmoid
__global__ void final_kernel(const float* __restrict__ part, const float* __restrict__ Wo,
                             const float* __restrict__ bo, const float* __restrict__ y,
                             float* __restrict__ out) {
    __shared__ float ls[16];
    int w = threadIdx.x >> 6, lane = threadIdx.x & 63;
    float m0 = part[(size_t)w * 128 + lane];
    float m1 = part[(size_t)w * 128 + 64 + lane];
    float p = m0 * Wo[lane] + m1 * Wo[64 + lane];
#pragma unroll
    for (int off = 32; off > 0; off >>= 1) p += __shfl_down(p, off);
    if (lane == 0) ls[w] = p + bo[0];
    __syncthreads();
    if (threadIdx.x < 16) {
        float l = ls[threadIdx.x];
        out[1 + threadIdx.x] = 1.f / (1.f + expf(-l));
    }
    if (threadIdx.x == 0) {
        float s = 0.f;
        for (int b = 0; b < 16; b++) {
            float l = ls[b];
            s += fmaxf(l, 0.f) - l * y[b] + log1pf(expf(-fabsf(l)));
        }
        out[0] = s / 16.f;
    }
}

extern "C" void kernel_launch(void* const* d_in, const int* in_sizes, int n_in,
                              void* d_out, int out_size, void* d_ws, size_t ws_size,
                              hipStream_t stream) {
    const int* word_ids = (const int*)d_in[0];
    const int* topic_ids = (const int*)d_in[1];
    const int* doc_graph_id = (const int*)d_in[2];
    const int* ww_src = (const int*)d_in[3];
    const int* ww_dst = (const int*)d_in[4];
    const float* ww_w = (const float*)d_in[5];
    const int* wt_src = (const int*)d_in[6];
    const int* wt_dst = (const int*)d_in[7];
    const float* wt_w = (const float*)d_in[8];
    const int* wd_src = (const int*)d_in[9];
    const int* wd_dst = (const int*)d_in[10];
    const float* wd_w = (const float*)d_in[11];
    const int* td_src = (const int*)d_in[12];
    const int* td_dst = (const int*)d_in[13];
    const float* td_w = (const float*)d_in[14];
    const int* tt_src = (const int*)d_in[15];
    const int* tt_dst = (const int*)d_in[16];
    const float* tt_w = (const float*)d_in[17];
    const float* word_embeds = (const float*)d_in[18];
    const float* topic_embeds = (const float*)d_in[19];
    const float* W_adapt = (const float*)d_in[20];
    const float* b_adapt = (const float*)d_in[21];
    const float* W1 = (const float*)d_in[22];
    const float* b1 = (const float*)d_in[23];
    const float* W2 = (const float*)d_in[24];
    const float* b2 = (const float*)d_in[25];
    const float* W_out = (const float*)d_in[26];
    const float* b_out = (const float*)d_in[27];
    const float* y_data = (const float*)d_in[28];
    float* out = (float*)d_out;

    const int E_ww = in_sizes[3], E_wt = in_sizes[6], E_wd = in_sizes[9];
    const int E_td = in_sizes[12], E_tt = in_sizes[15];

    // bucket configs: {lg, nbkt, stride}
    const int LG_WW = 9, NBK_WW = 196, ST_WW = 6144;
    const int LG_WT = 4, NBK_WT = 50,  ST_WT = 6656;
    const int LG_TT = 6, NBK_TT = 13,  ST_TT = 3712;
    const int LG_WD = 6, NBK_WD = 125, ST_WD = 4608;
    const int LG_TD = 8, NBK_TD = 32,  ST_TD = 3712;

    // -------- workspace --------
    float* ws = (float*)d_ws;
    size_t o = 0;
    auto alloc = [&](size_t n) { float* p = ws + o; o += (n + 63) & ~(size_t)63; return p; };
    bf16* pv1 = (bf16*)alloc((size_t)VOCAB * 64);
    bf16* pt1 = (bf16*)alloc((size_t)NTOPIC * 64);
    bf16* hw1 = (bf16*)alloc((size_t)NW * 64);
    bf16* ht1 = (bf16*)alloc((size_t)NT * 64);
    // zeroed region: bucket cursors + part (atomicMax accumulator); P1t pad zeroed in k2
    int* bk_ww = (int*)alloc(NBK_WW);
    int* bk_wt = (int*)alloc(NBK_WT);
    int* bk_tt = (int*)alloc(NBK_TT);
    int* bk_wd = (int*)alloc(NBK_WD);
    int* bk_td = (int*)alloc(NBK_TD);
    float* part = alloc((size_t)NB * 128);
    float* zero_end = ws + o;
    bf16* P1t = (bf16*)alloc(128 * 320 / 2);   // bf16 [128][320]
    int* bkb_ww = (int*)alloc(NBK_WW);
    int* bkb_wt = (int*)alloc(NBK_WT);
    int* bkb_tt = (int*)alloc(NBK_TT);
    int* bkb_wd = (int*)alloc(NBK_WD);
    int* bkb_td = (int*)alloc(NBK_TD);
    int* cnt_ww = (int*)alloc(NW);
    int* cnt_wt = (int*)alloc(NT);
    int* cnt_tt = (int*)alloc(NT);
    int* cnt_wd = (int*)alloc(ND);
    int* cnt_td = (int*)alloc(ND);
    int* off_ww = (int*)alloc(NW);
    int* off_wt = (int*)alloc(NT);
    int* off_tt = (int*)alloc(NT);
    int* off_wd = (int*)alloc(ND);
    int* off_td = (int*)alloc(ND);
    uint2* cs_ww = (uint2*)alloc((size_t)E_ww * 2);
    uint2* cs_wt = (uint2*)alloc((size_t)E_wt * 2);
    uint2* cs_tt = (uint2*)alloc((size_t)E_tt * 2);
    uint2* cs_wd = (uint2*)alloc((size_t)E_wd * 2);
    uint2* cs_td = (uint2*)alloc((size_t)E_td * 2);
    uint2* sc_ww = (uint2*)alloc((size_t)NBK_WW * ST_WW * 2);
    uint2* sc_wt = (uint2*)alloc((size_t)NBK_WT * ST_WT * 2);
    uint2* sc_tt = (uint2*)alloc((size_t)NBK_TT * ST_TT * 2);
    uint2* sc_wd = (uint2*)alloc((size_t)NBK_WD * ST_WD * 2);
    uint2* sc_td = (uint2*)alloc((size_t)NBK_TD * ST_TD * 2);
    float* U1 = alloc(HINP * 128);
    float* V1 = alloc(128 * 128);
    float* X2 = alloc(128 * 128);
    float* A_t1 = alloc(128 * 128);
    float* A_w2 = alloc(128 * 128);
    float* A_t2 = alloc(128 * 128);
    float* t1v = alloc(128);
    float* uv = alloc(128);
    float* t2v = alloc(128);
    float* b_t1 = alloc(128);
    float* b_t2 = alloc(128);
    float* bv1 = alloc(128);
    float* b_w2 = alloc(128);
    (void)ws_size; (void)n_in; (void)out_size;

    Et eww = {ww_src, ww_dst, ww_w, word_ids,  cnt_ww, off_ww, bk_ww, bkb_ww, sc_ww, cs_ww, E_ww, LG_WW, NBK_WW, ST_WW, NW};
    Et ewt = {wt_src, wt_dst, wt_w, word_ids,  cnt_wt, off_wt, bk_wt, bkb_wt, sc_wt, cs_wt, E_wt, LG_WT, NBK_WT, ST_WT, NT};
    Et ett = {tt_src, tt_dst, tt_w, topic_ids, cnt_tt, off_tt, bk_tt, bkb_tt, sc_tt, cs_tt, E_tt, LG_TT, NBK_TT, ST_TT, NT};
    Et ewd = {wd_src, wd_dst, wd_w, nullptr,   cnt_wd, off_wd, bk_wd, bkb_wd, sc_wd, cs_wd, E_wd, LG_WD, NBK_WD, ST_WD, ND};
    Et etd = {td_src, td_dst, td_w, nullptr,   cnt_td, off_td, bk_td, bkb_td, sc_td, cs_td, E_td, LG_TD, NBK_TD, ST_TD, ND};

    // -------- memset bucket cursors + part (10.5 KB) --------
    hipMemsetAsync(bk_ww, 0, (char*)zero_end - (char*)bk_ww, stream);

    // -------- K1: F1 (2048 edges/block, vectorized) | prep level-1 --------
    int f0 = (E_ww + EPB - 1) / EPB, f1b = f0 + (E_wt + EPB - 1) / EPB;
    int f2b = f1b + (E_tt + EPB - 1) / EPB, f3b = f2b + (E_wd + EPB - 1) / EPB;
    int f4b = f3b + (E_td + EPB - 1) / EPB;
    k1_kernel<<<f4b + 409, 256, 0, stream>>>(eww, ewt, ett, ewd, etd,
                                             f0, f1b, f2b, f3b, f4b,
                                             W1, b1, W2, b2, W_adapt, b_adapt,
                                             U1, V1, A_t1, X2, A_t2,
                                             t1v, uv, t2v, b_t1, b_t2);

    // -------- K2: bucket scans | prep level-2 (emits P1t bf16 transposed, incl. zero pad) --------
    k2_kernel<<<230, 256, 0, stream>>>(eww, ewt, ett, ewd, etd,
                                       W1, b1, W2, b2, U1, V1, X2, t1v, uv, t2v,
                                       P1t, A_w2, bv1, b_w2);

    // -------- K3: pv MFMA | pt | F2 CSR pass --------
    int g0 = NBK_WW, g1 = g0 + NBK_WT, g2 = g1 + NBK_TT, g3 = g2 + NBK_WD, g4 = g3 + NBK_TD;
    k3_kernel<<<NBPVM + NBPT + g4, 256, 0, stream>>>(
        eww, ewt, ett, ewd, etd, g0, g1, g2, g3, g4,
        word_embeds, P1t, bv1, pv1, topic_embeds, A_t1, b_t1, pt1);

    // -------- K4: layer-1 aggregation (topics first, then ww; 16 word rows/block) --------
    aggA_kernel<<<NT + NW / 16, 256, 0, stream>>>(
        (const uint4*)pv1, (const uint4*)pt1,
        cs_ww, off_ww, cnt_ww, (uint4*)hw1,
        cs_wt, off_wt, cnt_wt,
        cs_tt, off_tt, cnt_tt, (uint4*)ht1);

    // -------- K5: fused layer-2 aggregation + doc projection + doc pool (8 docs/block) --------
    aggBdoc_kernel<<<ND / 8, 256, 0, stream>>>(
        (const uint4*)hw1, (const uint4*)ht1,
        cs_wd, off_wd, cnt_wd,
        cs_td, off_td, cnt_td,
        A_w2, b_w2, A_t2, b_t2, doc_graph_id, part);

    // -------- readout --------
    final_kernel<<<1, 1024, 0, stream>>>(part, W_out, b_out, y_data, out);
}